// Round 5
// baseline (230.659 us; speedup 1.0000x reference)
//
#include <hip/hip_runtime.h>

#define NB 64
#define NT 512
#define NC 13
#define AP 136    // A row stride (ush)
#define WP 72     // W row stride (ush)
#define USTRIDE 18432            // ush per W unit (hi 9216 + lo 9216)
#define DWT_H   552960           // 30*18432
#define DWT_L   563200           // DWT_H + 5*2048
#define WS_NEED 1146880          // bytes = (DWT_L + 5*2048)*2

typedef short s8v __attribute__((ext_vector_type(8)));
typedef float f4v __attribute__((ext_vector_type(4)));
typedef unsigned short ush;
typedef unsigned int u32;

__device__ __forceinline__ ush f2bf(float f){
    union { float f; u32 u; } v; v.f = f;
    u32 r = v.u + 0x7fffu + ((v.u >> 16) & 1u);
    return (ush)(r >> 16);
}
__device__ __forceinline__ float bf2f(ush h){
    union { u32 u; float f; } v; v.u = ((u32)h) << 16; return v.f;
}

// ---- prep: pre-split W (and dwT) into ws, in pot's exact LDS layout ----
__global__ __launch_bounds__(512)
void prep_kernel(const float* __restrict__ cw1, const float* __restrict__ cw2,
                 const float* __restrict__ cw3, const float* __restrict__ cw4,
                 const float* __restrict__ cw5, const float* __restrict__ dense_w,
                 ush* __restrict__ ws)
{
    int bx = blockIdx.x, tid = threadIdx.x;
    if (bx < 240) {
        int u = bx >> 3, chunk = bx & 7;
        int ut = u >> 1, eh = u & 1;
        int fb = ut<1?0: ut<3?1: ut<6?2: ut<10?3:4;
        int jj = ut - fb*(fb+1)/2;
        const float* cw = fb==0?cw1: fb==1?cw2: fb==2?cw3: fb==3?cw4: cw5;
        #pragma unroll
        for (int q = 0; q < 2; ++q) {
            int idx = chunk*1024 + q*512 + tid;     // 0..8191
            int f = idx >> 6, e = idx & 63;
            float w = cw[(jj*128 + eh*64 + e)*128 + f];
            ush hi = f2bf(w);
            ws[u*USTRIDE + f*WP + e]        = hi;
            ws[u*USTRIDE + 9216 + f*WP + e] = f2bf(w - bf2f(hi));
        }
    } else {
        int fb = bx - 240;
        #pragma unroll
        for (int q = 0; q < 4; ++q) {
            int idx = q*512 + tid;                  // 0..2047, = c*128+f
            int c = idx >> 7, f = idx & 127;
            float v = (c < 13) ? dense_w[(fb*128 + f)*13 + c] : 0.f;
            ush hi = f2bf(v);
            ws[DWT_H + fb*2048 + idx] = hi;
            ws[DWT_L + fb*2048 + idx] = f2bf(v - bf2f(hi));
        }
    }
}

// ---- pot v5: ws-fed W staging + register prefetch ----
__global__ __launch_bounds__(512)
void pot_kernel_ws(const int* __restrict__ input_char,
                   const int* __restrict__ input_script,
                   const float* __restrict__ char_emb,
                   const float* __restrict__ uscript_emb,
                   const float* __restrict__ dense_w,
                   const float* __restrict__ dense_b,
                   const float* __restrict__ left_b,
                   const float* __restrict__ right_b,
                   const float* __restrict__ cb1, const float* __restrict__ cb2,
                   const float* __restrict__ cb3, const float* __restrict__ cb4,
                   const float* __restrict__ cb5,
                   const ush* __restrict__ ws,
                   float* __restrict__ out_pot)
{
    __shared__ __align__(16) ush smem[76256];           // 152512 B
    ush* Ah     = smem;                                 // 132 x AP
    ush* Al     = smem + 17952;
    ush* Wh     = smem + 35904;                         // 128 x WP
    ush* Wl     = smem + 45120;
    ush* feat_h = smem + 54336;                         // 64 x AP
    ush* feat_l = smem + 63040;
    float* uebt = (float*)(smem + 71744);               // 16 x 128 fp32
    float* dwue = (float*)(smem + 75840);               // 16 x 13 fp32

    const int tid  = threadIdx.x;
    const int lane = tid & 63;
    const int wid  = tid >> 6;
    const int tg   = wid >> 2;
    const int fg   = wid & 3;
    const int lr   = lane & 15;
    const int lq   = lane >> 4;
    const int bb   = blockIdx.x >> 2;
    const int t0   = (blockIdx.x & 3) << 7;

    // ---- stage A: emb rows t0-2 .. t0+129, fp32 -> bf16 hi/lo ----
    for (int i = tid; i < 132*16; i += 512) {
        int row = i >> 4, s = (i & 15) << 3;
        int t = t0 + row - 2;
        uint4 hv = {0,0,0,0}, lv = {0,0,0,0};
        if (t >= 0 && t < NT) {
            int ch = input_char[bb*NT + t];
            const float* src = char_emb + ch*128 + s;
            float4 x0 = *(const float4*)src;
            float4 x1 = *(const float4*)(src + 4);
            float fs[8] = {x0.x,x0.y,x0.z,x0.w,x1.x,x1.y,x1.z,x1.w};
            ush h[8], l[8];
            #pragma unroll
            for (int q = 0; q < 8; ++q) {
                h[q] = f2bf(fs[q]);
                l[q] = f2bf(fs[q] - bf2f(h[q]));
            }
            hv.x = h[0] | ((u32)h[1]<<16); hv.y = h[2] | ((u32)h[3]<<16);
            hv.z = h[4] | ((u32)h[5]<<16); hv.w = h[6] | ((u32)h[7]<<16);
            lv.x = l[0] | ((u32)l[1]<<16); lv.y = l[2] | ((u32)l[3]<<16);
            lv.z = l[4] | ((u32)l[5]<<16); lv.w = l[6] | ((u32)l[7]<<16);
        }
        *(uint4*)&Ah[row*AP + s] = hv;
        *(uint4*)&Al[row*AP + s] = lv;
    }
    // ---- stage uebt / dwue (fp32, exact) ----
    for (int i = tid; i < 2048; i += 512) {
        int uu = i >> 7, tl = i & 127;
        uebt[uu*128 + tl] = uscript_emb[input_script[bb*NT + t0 + tl]*16 + uu];
    }
    if (tid < 208) dwue[tid] = dense_w[640*13 + tid];
    // ---- stage W unit 0 (straight copy) ----
    {
        const uint4* s0 = (const uint4*)ws;
        uint4* dst = (uint4*)Wh;
        #pragma unroll
        for (int q = 0; q < 5; ++q) {
            int i = tid + q*512;
            if (i < 2304) dst[i] = s0[i];
        }
    }
    __syncthreads();

    const float* cbs[5] = {cb1, cb2, cb3, cb4, cb5};

    f4v cacc[4][2];
    #pragma unroll
    for (int mt = 0; mt < 4; ++mt)
        #pragma unroll
        for (int nt = 0; nt < 2; ++nt) cacc[mt][nt] = (f4v){0.f,0.f,0.f,0.f};
    f4v dacc = (f4v){0.f,0.f,0.f,0.f};

    #pragma unroll 1
    for (int u = 0; u < 30; ++u) {
        int ut  = u >> 1, eh = u & 1;
        int fb  = ut<1?0: ut<3?1: ut<6?2: ut<10?3:4;
        int jj  = ut - fb*(fb+1)/2;
        int jsh = (2 - (fb >> 1)) + jj;

        // ---- prefetch next W unit into registers (overlaps MFMA below) ----
        uint4 pre[5];
        if (u < 29) {
            const uint4* src = (const uint4*)(ws + (u + 1)*USTRIDE);
            #pragma unroll
            for (int q = 0; q < 5; ++q) {
                int i = tid + q*512;
                if (i < 2304) pre[q] = src[i];
            }
        }

        // ---- conv MFMA: 48 per wave ----
        #pragma unroll
        for (int kk = 0; kk < 2; ++kk) {
            int ko = kk*32 + (lq << 3);
            s8v bh[2], bl[2];
            #pragma unroll
            for (int nt = 0; nt < 2; ++nt) {
                int frow = fg*32 + nt*16 + lr;
                bh[nt] = *(const s8v*)&Wh[frow*WP + ko];
                bl[nt] = *(const s8v*)&Wl[frow*WP + ko];
            }
            #pragma unroll
            for (int mt = 0; mt < 4; ++mt) {
                int row = tg*64 + mt*16 + lr + jsh;
                int ai  = row*AP + eh*64 + ko;
                s8v ah = *(const s8v*)&Ah[ai];
                s8v al = *(const s8v*)&Al[ai];
                #pragma unroll
                for (int nt = 0; nt < 2; ++nt) {
                    cacc[mt][nt] = __builtin_amdgcn_mfma_f32_16x16x32_bf16(ah, bh[nt], cacc[mt][nt], 0,0,0);
                    cacc[mt][nt] = __builtin_amdgcn_mfma_f32_16x16x32_bf16(ah, bl[nt], cacc[mt][nt], 0,0,0);
                    cacc[mt][nt] = __builtin_amdgcn_mfma_f32_16x16x32_bf16(al, bh[nt], cacc[mt][nt], 0,0,0);
                }
            }
        }

        // ---- end of an f-block: ReLU -> feat -> dense MFMA (dwT from ws) ----
        if (u == 1 || u == 5 || u == 11 || u == 19 || u == 29) {
            float cbv0 = cbs[fb][fg*32 + lr];
            float cbv1 = cbs[fb][fg*32 + 16 + lr];

            #pragma unroll 1
            for (int h = 0; h < 2; ++h) {
                if (tg == h) {
                    #pragma unroll
                    for (int mt = 0; mt < 4; ++mt)
                        #pragma unroll
                        for (int nt = 0; nt < 2; ++nt)
                            #pragma unroll
                            for (int r = 0; r < 4; ++r) {
                                float v = fmaxf(cacc[mt][nt][r] + (nt ? cbv1 : cbv0), 0.f);
                                int rw = mt*16 + (lq << 2) + r;       // local t in half
                                int f  = fg*32 + nt*16 + lr;
                                ush hh = f2bf(v);
                                feat_h[rw*AP + f] = hh;
                                feat_l[rw*AP + f] = f2bf(v - bf2f(hh));
                            }
                }
                __syncthreads();
                if (tg == h) {
                    int trow = fg*16 + lr;                            // local t in half
                    #pragma unroll
                    for (int kf = 0; kf < 4; ++kf) {
                        int f0 = kf*32 + (lq << 3);
                        s8v a2h = *(const s8v*)&ws[DWT_H + fb*2048 + lr*128 + f0];
                        s8v a2l = *(const s8v*)&ws[DWT_L + fb*2048 + lr*128 + f0];
                        s8v b2h = *(const s8v*)&feat_h[trow*AP + f0];
                        s8v b2l = *(const s8v*)&feat_l[trow*AP + f0];
                        dacc = __builtin_amdgcn_mfma_f32_16x16x32_bf16(a2h, b2h, dacc, 0,0,0);
                        dacc = __builtin_amdgcn_mfma_f32_16x16x32_bf16(a2h, b2l, dacc, 0,0,0);
                        dacc = __builtin_amdgcn_mfma_f32_16x16x32_bf16(a2l, b2h, dacc, 0,0,0);
                    }
                    if (fb == 4) {
                        int tloc  = tg*64 + fg*16 + lr;
                        int tglob = t0 + tloc;
                        float pc[4];
                        #pragma unroll
                        for (int r = 0; r < 4; ++r) pc[r] = dacc[r];
                        #pragma unroll
                        for (int uu = 0; uu < 16; ++uu) {
                            float uv = uebt[uu*128 + tloc];
                            #pragma unroll
                            for (int r = 0; r < 4; ++r) {
                                int c = (lq << 2) + r;
                                if (c < 13) pc[r] = fmaf(uv, dwue[uu*13 + c], pc[r]);
                            }
                        }
                        #pragma unroll
                        for (int r = 0; r < 4; ++r) {
                            int c = (lq << 2) + r;
                            if (c < 13) {
                                float v = pc[r] + dense_b[c];
                                if (tglob == 0)    v += left_b[c];
                                if (tglob == NT-1) v += right_b[c];
                                out_pot[(bb*NT + tglob)*13 + c] = v;
                            }
                        }
                    }
                }
                __syncthreads();
            }
            #pragma unroll
            for (int mt = 0; mt < 4; ++mt)
                #pragma unroll
                for (int nt = 0; nt < 2; ++nt) cacc[mt][nt] = (f4v){0.f,0.f,0.f,0.f};
        } else {
            __syncthreads();   // conv reads of Wh/Wl done
        }

        // ---- write prefetched W unit to LDS ----
        if (u < 29) {
            uint4* dst = (uint4*)Wh;
            #pragma unroll
            for (int q = 0; q < 5; ++q) {
                int i = tid + q*512;
                if (i < 2304) dst[i] = pre[q];
            }
        }
        __syncthreads();
    }
}

// ---- fallback pot (round-4 verbatim, used if ws_size too small) ----
__global__ __launch_bounds__(512)
void pot_kernel_fb(const int* __restrict__ input_char,
                   const int* __restrict__ input_script,
                   const float* __restrict__ char_emb,
                   const float* __restrict__ uscript_emb,
                   const float* __restrict__ dense_w,
                   const float* __restrict__ dense_b,
                   const float* __restrict__ left_b,
                   const float* __restrict__ right_b,
                   const float* __restrict__ cw1, const float* __restrict__ cb1,
                   const float* __restrict__ cw2, const float* __restrict__ cb2,
                   const float* __restrict__ cw3, const float* __restrict__ cb3,
                   const float* __restrict__ cw4, const float* __restrict__ cb4,
                   const float* __restrict__ cw5, const float* __restrict__ cb5,
                   float* __restrict__ out_pot)
{
    __shared__ __align__(16) ush smem[71744];
    ush* Ah     = smem;
    ush* Al     = smem + 17952;
    ush* Wh     = smem + 35904;
    ush* Wl     = smem + 45120;
    ush* feat_h = smem + 54336;
    ush* feat_l = smem + 63040;
    float* dwlds = (float*)(smem + 35904);
    float* dwue  = (float*)(smem + 39232);
    float* uebt  = (float*)(smem + 39648);

    const int tid  = threadIdx.x;
    const int lane = tid & 63;
    const int wid  = tid >> 6;
    const int tg   = wid >> 2;
    const int fg   = wid & 3;
    const int lr   = lane & 15;
    const int lq   = lane >> 4;
    const int bb   = blockIdx.x >> 2;
    const int t0   = (blockIdx.x & 3) << 7;

    for (int i = tid; i < 132*16; i += 512) {
        int row = i >> 4, s = (i & 15) << 3;
        int t = t0 + row - 2;
        uint4 hv = {0,0,0,0}, lv = {0,0,0,0};
        if (t >= 0 && t < NT) {
            int ch = input_char[bb*NT + t];
            const float* src = char_emb + ch*128 + s;
            float4 x0 = *(const float4*)src;
            float4 x1 = *(const float4*)(src + 4);
            float fs[8] = {x0.x,x0.y,x0.z,x0.w,x1.x,x1.y,x1.z,x1.w};
            ush h[8], l[8];
            #pragma unroll
            for (int q = 0; q < 8; ++q) {
                h[q] = f2bf(fs[q]);
                l[q] = f2bf(fs[q] - bf2f(h[q]));
            }
            hv.x = h[0] | ((u32)h[1]<<16); hv.y = h[2] | ((u32)h[3]<<16);
            hv.z = h[4] | ((u32)h[5]<<16); hv.w = h[6] | ((u32)h[7]<<16);
            lv.x = l[0] | ((u32)l[1]<<16); lv.y = l[2] | ((u32)l[3]<<16);
            lv.z = l[4] | ((u32)l[5]<<16); lv.w = l[6] | ((u32)l[7]<<16);
        }
        *(uint4*)&Ah[row*AP + s] = hv;
        *(uint4*)&Al[row*AP + s] = lv;
    }

    const float* cws[5] = {cw1, cw2, cw3, cw4, cw5};
    const float* cbs[5] = {cb1, cb2, cb3, cb4, cb5};

    f4v cacc[4][2];
    #pragma unroll
    for (int mt = 0; mt < 4; ++mt)
        #pragma unroll
        for (int nt = 0; nt < 2; ++nt) cacc[mt][nt] = (f4v){0.f,0.f,0.f,0.f};
    f4v dacc = (f4v){0.f,0.f,0.f,0.f};

    #pragma unroll 1
    for (int u = 0; u < 30; ++u) {
        int ut  = u >> 1, eh = u & 1;
        int fb  = ut<1?0: ut<3?1: ut<6?2: ut<10?3:4;
        int jj  = ut - fb*(fb+1)/2;
        int jsh = (2 - (fb >> 1)) + jj;
        const float* cw = cws[fb] + (jj*128 + eh*64)*128;

        __syncthreads();
        for (int g = tid; g < 1024; g += 512) {
            int f = g & 127, e8 = (g >> 7) << 3;
            float v[8];
            #pragma unroll
            for (int q = 0; q < 8; ++q) v[q] = cw[(e8 + q)*128 + f];
            ush h8[8], l8[8];
            #pragma unroll
            for (int q = 0; q < 8; ++q) {
                h8[q] = f2bf(v[q]);
                l8[q] = f2bf(v[q] - bf2f(h8[q]));
            }
            uint4 hv, lv;
            hv.x = h8[0] | ((u32)h8[1]<<16); hv.y = h8[2] | ((u32)h8[3]<<16);
            hv.z = h8[4] | ((u32)h8[5]<<16); hv.w = h8[6] | ((u32)h8[7]<<16);
            lv.x = l8[0] | ((u32)l8[1]<<16); lv.y = l8[2] | ((u32)l8[3]<<16);
            lv.z = l8[4] | ((u32)l8[5]<<16); lv.w = l8[6] | ((u32)l8[7]<<16);
            *(uint4*)&Wh[f*WP + e8] = hv;
            *(uint4*)&Wl[f*WP + e8] = lv;
        }
        __syncthreads();

        #pragma unroll
        for (int kk = 0; kk < 2; ++kk) {
            int ko = kk*32 + (lq << 3);
            s8v bh[2], bl[2];
            #pragma unroll
            for (int nt = 0; nt < 2; ++nt) {
                int frow = fg*32 + nt*16 + lr;
                bh[nt] = *(const s8v*)&Wh[frow*WP + ko];
                bl[nt] = *(const s8v*)&Wl[frow*WP + ko];
            }
            #pragma unroll
            for (int mt = 0; mt < 4; ++mt) {
                int row = tg*64 + mt*16 + lr + jsh;
                int ai  = row*AP + eh*64 + ko;
                s8v ah = *(const s8v*)&Ah[ai];
                s8v al = *(const s8v*)&Al[ai];
                #pragma unroll
                for (int nt = 0; nt < 2; ++nt) {
                    cacc[mt][nt] = __builtin_amdgcn_mfma_f32_16x16x32_bf16(ah, bh[nt], cacc[mt][nt], 0,0,0);
                    cacc[mt][nt] = __builtin_amdgcn_mfma_f32_16x16x32_bf16(ah, bl[nt], cacc[mt][nt], 0,0,0);
                    cacc[mt][nt] = __builtin_amdgcn_mfma_f32_16x16x32_bf16(al, bh[nt], cacc[mt][nt], 0,0,0);
                }
            }
        }

        if (u == 1 || u == 5 || u == 11 || u == 19 || u == 29) {
            __syncthreads();
            for (int i = tid; i < 128*13; i += 512)
                dwlds[i] = dense_w[fb*128*13 + i];
            if (fb == 4) {
                for (int i = tid; i < 16*13; i += 512)
                    dwue[i] = dense_w[640*13 + i];
                for (int i = tid; i < 2048; i += 512) {
                    int uu = i >> 7, tl = i & 127;
                    uebt[uu*128 + tl] = uscript_emb[input_script[bb*NT + t0 + tl]*16 + uu];
                }
            }
            __syncthreads();

            float cbv0 = cbs[fb][fg*32 + lr];
            float cbv1 = cbs[fb][fg*32 + 16 + lr];

            #pragma unroll 1
            for (int h = 0; h < 2; ++h) {
                if (tg == h) {
                    #pragma unroll
                    for (int mt = 0; mt < 4; ++mt)
                        #pragma unroll
                        for (int nt = 0; nt < 2; ++nt)
                            #pragma unroll
                            for (int r = 0; r < 4; ++r) {
                                float v = fmaxf(cacc[mt][nt][r] + (nt ? cbv1 : cbv0), 0.f);
                                int rw = mt*16 + (lq << 2) + r;
                                int f  = fg*32 + nt*16 + lr;
                                ush hh = f2bf(v);
                                feat_h[rw*AP + f] = hh;
                                feat_l[rw*AP + f] = f2bf(v - bf2f(hh));
                            }
                }
                __syncthreads();
                if (tg == h) {
                    int trow = fg*16 + lr;
                    #pragma unroll
                    for (int kf = 0; kf < 4; ++kf) {
                        int f0 = kf*32 + (lq << 3);
                        float dv[8];
                        #pragma unroll
                        for (int q = 0; q < 8; ++q) dv[q] = dwlds[(f0 + q)*13 + lr];
                        s8v a2h, a2l;
                        #pragma unroll
                        for (int q = 0; q < 8; ++q) {
                            ush hh = f2bf(dv[q]);
                            a2h[q] = (short)hh;
                            a2l[q] = (short)f2bf(dv[q] - bf2f(hh));
                        }
                        s8v b2h = *(const s8v*)&feat_h[trow*AP + f0];
                        s8v b2l = *(const s8v*)&feat_l[trow*AP + f0];
                        dacc = __builtin_amdgcn_mfma_f32_16x16x32_bf16(a2h, b2h, dacc, 0,0,0);
                        dacc = __builtin_amdgcn_mfma_f32_16x16x32_bf16(a2h, b2l, dacc, 0,0,0);
                        dacc = __builtin_amdgcn_mfma_f32_16x16x32_bf16(a2l, b2h, dacc, 0,0,0);
                    }
                    if (fb == 4) {
                        int tloc  = tg*64 + fg*16 + lr;
                        int tglob = t0 + tloc;
                        float pc[4];
                        #pragma unroll
                        for (int r = 0; r < 4; ++r) pc[r] = dacc[r];
                        #pragma unroll
                        for (int uu = 0; uu < 16; ++uu) {
                            float uv = uebt[uu*128 + tloc];
                            #pragma unroll
                            for (int r = 0; r < 4; ++r) {
                                int c = (lq << 2) + r;
                                if (c < 13) pc[r] = fmaf(uv, dwue[uu*13 + c], pc[r]);
                            }
                        }
                        #pragma unroll
                        for (int r = 0; r < 4; ++r) {
                            int c = (lq << 2) + r;
                            if (c < 13) {
                                float v = pc[r] + dense_b[c];
                                if (tglob == 0)    v += left_b[c];
                                if (tglob == NT-1) v += right_b[c];
                                out_pot[(bb*NT + tglob)*13 + c] = v;
                            }
                        }
                    }
                }
                __syncthreads();
            }
            #pragma unroll
            for (int mt = 0; mt < 4; ++mt)
                #pragma unroll
                for (int nt = 0; nt < 2; ++nt) cacc[mt][nt] = (f4v){0.f,0.f,0.f,0.f};
        }
    }
}

// ---------------- viterbi (round-2 version, proven) ----------------
__global__ __launch_bounds__(256)
void viterbi_kernel(const float* __restrict__ pot,
                    const float* __restrict__ trans,
                    float* __restrict__ out_dec,
                    float* __restrict__ out_seq,
                    float* __restrict__ out_trans)
{
    __shared__ __align__(16) float s_lds[NT * NC];
    __shared__ float t_lds[NC * NC];
    __shared__ unsigned char path_lds[16 * 13 * 32];
    __shared__ unsigned char entry_lds[16 * 13];
    __shared__ int chunk_e[16];

    const int b   = blockIdx.x;
    const int tid = threadIdx.x;

    {
        const float4* src = reinterpret_cast<const float4*>(pot + b * NT * NC);
        float4* dst = reinterpret_cast<float4*>(s_lds);
        for (int i = tid; i < NT * NC / 4; i += 256) dst[i] = src[i];
        for (int i = tid; i < NC * NC; i += 256) t_lds[i] = trans[i];
    }
    __syncthreads();

    if (tid < 64) {
        const int c = tid;
        const bool act = c < NC;
        float tc[13];
        #pragma unroll
        for (int p = 0; p < NC; ++p) tc[p] = t_lds[p * NC + (act ? c : 0)];
        float s = act ? s_lds[c] : -1e30f;

        for (int t = 1; t < NT; ++t) {
            float v[13];
            #pragma unroll
            for (int p = 0; p < NC; ++p) v[p] = __shfl(s, p) + tc[p];
            float m0 = fmaxf(fmaxf(v[0], v[1]), fmaxf(v[2], v[3]));
            float m1 = fmaxf(fmaxf(v[4], v[5]), fmaxf(v[6], v[7]));
            float m2 = fmaxf(fmaxf(v[8], v[9]), fmaxf(v[10], v[11]));
            float best = fmaxf(fmaxf(m0, m1), fmaxf(m2, v[12]));
            float pv = act ? s_lds[t * NC + c] : 0.f;
            s = best + pv;
            if (act) s_lds[t * NC + c] = s;
        }
    }
    __syncthreads();

    if (tid < 16 * 13) {
        const int chunk = tid / 13;
        const int e     = tid - chunk * 13;
        unsigned char* path = &path_lds[(chunk * 13 + e) * 32];
        int cur = e;
        path[31] = (unsigned char)e;
        for (int tl = 31; tl >= 1; --tl) {
            const float* srow = &s_lds[(chunk * 32 + tl - 1) * NC];
            float best = -1e30f; int bi = 0;
            #pragma unroll
            for (int p = 0; p < NC; ++p) {
                float v = srow[p] + t_lds[p * NC + cur];
                if (v > best) { best = v; bi = p; }   // first-max (jnp.argmax)
            }
            cur = bi;
            path[tl - 1] = (unsigned char)cur;
        }
        if (chunk > 0) {
            const float* srow = &s_lds[(chunk * 32 - 1) * NC];
            float best = -1e30f; int bi = 0;
            #pragma unroll
            for (int p = 0; p < NC; ++p) {
                float v = srow[p] + t_lds[p * NC + cur];
                if (v > best) { best = v; bi = p; }
            }
            entry_lds[chunk * 13 + e] = (unsigned char)bi;
        }
    }
    __syncthreads();

    if (tid == 0) {
        float best = -1e30f; int last = 0;
        for (int c = 0; c < NC; ++c) {
            float v = s_lds[(NT - 1) * NC + c];
            if (v > best) { best = v; last = c; }
        }
        chunk_e[15] = last;
        for (int i = 15; i >= 1; --i)
            chunk_e[i - 1] = entry_lds[i * 13 + chunk_e[i]];
    }
    __syncthreads();

    float* dec = out_dec + b * NT;
    for (int t = tid; t < NT; t += 256) {
        int ck = t >> 5;
        dec[t] = (float)path_lds[(ck * 13 + chunk_e[ck]) * 32 + (t & 31)];
    }
    if (tid == 0) out_seq[b] = (float)NT;
    if (b == 0) {
        for (int i = tid; i < NC * NC; i += 256) out_trans[i] = trans[i];
    }
}

extern "C" void kernel_launch(void* const* d_in, const int* in_sizes, int n_in,
                              void* d_out, int out_size, void* d_ws, size_t ws_size,
                              hipStream_t stream) {
    const int*   input_char   = (const int*)d_in[0];
    const int*   input_script = (const int*)d_in[1];
    const float* char_emb     = (const float*)d_in[3];
    const float* uscript_emb  = (const float*)d_in[4];
    const float* dense_w      = (const float*)d_in[5];
    const float* dense_b      = (const float*)d_in[6];
    const float* trans        = (const float*)d_in[7];
    const float* left_b       = (const float*)d_in[8];
    const float* right_b      = (const float*)d_in[9];
    const float* cw1 = (const float*)d_in[10];
    const float* cb1 = (const float*)d_in[11];
    const float* cw2 = (const float*)d_in[12];
    const float* cb2 = (const float*)d_in[13];
    const float* cw3 = (const float*)d_in[14];
    const float* cb3 = (const float*)d_in[15];
    const float* cw4 = (const float*)d_in[16];
    const float* cb4 = (const float*)d_in[17];
    const float* cw5 = (const float*)d_in[18];
    const float* cb5 = (const float*)d_in[19];

    float* out       = (float*)d_out;
    float* out_dec   = out;                       // [B,T] decoded tags (as float)
    float* out_pot   = out + NB * NT;             // [B,T,C]
    float* out_seq   = out_pot + NB * NT * NC;    // [B]
    float* out_trans = out_seq + NB;              // [C,C]

    if (ws_size >= (size_t)WS_NEED) {
        hipLaunchKernelGGL(prep_kernel, dim3(245), dim3(512), 0, stream,
                           cw1, cw2, cw3, cw4, cw5, dense_w, (ush*)d_ws);
        hipLaunchKernelGGL(pot_kernel_ws, dim3(256), dim3(512), 0, stream,
                           input_char, input_script, char_emb, uscript_emb,
                           dense_w, dense_b, left_b, right_b,
                           cb1, cb2, cb3, cb4, cb5,
                           (const ush*)d_ws, out_pot);
    } else {
        hipLaunchKernelGGL(pot_kernel_fb, dim3(256), dim3(512), 0, stream,
                           input_char, input_script, char_emb, uscript_emb,
                           dense_w, dense_b, left_b, right_b,
                           cw1, cb1, cw2, cb2, cw3, cb3, cw4, cb4, cw5, cb5,
                           out_pot);
    }

    hipLaunchKernelGGL(viterbi_kernel, dim3(NB), dim3(256), 0, stream,
                       out_pot, trans, out_dec, out_seq, out_trans);
}

// Round 6
// 163.351 us; speedup vs baseline: 1.4120x; 1.4120x over previous
//
#include <hip/hip_runtime.h>

#define NB 64
#define NT 512
#define NC 13
#define AP 136    // A row stride (ush)
#define WP 72     // W row stride (ush)
#define USTRIDE 18432            // ush per W unit (hi 9216 + lo 9216) = 36864 B
#define DWT_H   552960           // 30*18432
#define DWT_L   563200           // DWT_H + 5*2048
#define WS_NEED 1146880          // bytes

typedef short s8v __attribute__((ext_vector_type(8)));
typedef float f4v __attribute__((ext_vector_type(4)));
typedef unsigned short ush;
typedef unsigned int u32;

__device__ __forceinline__ ush f2bf(float f){
    union { float f; u32 u; } v; v.f = f;
    u32 r = v.u + 0x7fffu + ((v.u >> 16) & 1u);
    return (ush)(r >> 16);
}
__device__ __forceinline__ float bf2f(ush h){
    union { u32 u; float f; } v; v.u = ((u32)h) << 16; return v.f;
}

// ---- prep: pre-split W (+ dwT) into ws in pot's exact padded LDS layout ----
// blocks 0..29: one W unit each (coalesced reads, 16B writes). blocks 30..34: dwT.
__global__ __launch_bounds__(512)
void prep_kernel(const float* __restrict__ cw1, const float* __restrict__ cw2,
                 const float* __restrict__ cw3, const float* __restrict__ cw4,
                 const float* __restrict__ cw5, const float* __restrict__ dense_w,
                 ush* __restrict__ ws)
{
    int bx = blockIdx.x, tid = threadIdx.x;
    if (bx < 30) {
        int u = bx, ut = u >> 1, eh = u & 1;
        int fb = ut<1?0: ut<3?1: ut<6?2: ut<10?3:4;
        int jj = ut - fb*(fb+1)/2;
        const float* cw = fb==0?cw1: fb==1?cw2: fb==2?cw3: fb==3?cw4: cw5;
        #pragma unroll
        for (int it = 0; it < 2; ++it) {
            int g = it*512 + tid;            // 0..1023
            int f = g & 127;
            int e8 = (g >> 7) << 3;          // 0..56
            float v[8];
            #pragma unroll
            for (int q = 0; q < 8; ++q)
                v[q] = cw[(jj*128 + eh*64 + e8 + q)*128 + f];
            ush h8[8], l8[8];
            #pragma unroll
            for (int q = 0; q < 8; ++q) {
                h8[q] = f2bf(v[q]);
                l8[q] = f2bf(v[q] - bf2f(h8[q]));
            }
            uint4 hv, lv;
            hv.x = h8[0] | ((u32)h8[1]<<16); hv.y = h8[2] | ((u32)h8[3]<<16);
            hv.z = h8[4] | ((u32)h8[5]<<16); hv.w = h8[6] | ((u32)h8[7]<<16);
            lv.x = l8[0] | ((u32)l8[1]<<16); lv.y = l8[2] | ((u32)l8[3]<<16);
            lv.z = l8[4] | ((u32)l8[5]<<16); lv.w = l8[6] | ((u32)l8[7]<<16);
            *(uint4*)&ws[u*USTRIDE + f*WP + e8]        = hv;
            *(uint4*)&ws[u*USTRIDE + 9216 + f*WP + e8] = lv;
        }
    } else {
        int fb = bx - 30;
        #pragma unroll
        for (int it = 0; it < 4; ++it) {
            int idx = it*512 + tid;          // 0..2047 = c*128+f
            int c = idx >> 7, f = idx & 127;
            float v = (c < 13) ? dense_w[(fb*128 + f)*13 + c] : 0.f;
            ush hi = f2bf(v);
            ws[DWT_H + fb*2048 + idx] = hi;
            ws[DWT_L + fb*2048 + idx] = f2bf(v - bf2f(hi));
        }
    }
}

// ---- pot v6: gll double-buffered W staging (static LDS) ----
// 256 blocks (b = bx>>2, t0 = (bx&3)*128), 512 threads = 8 waves.
// buf0 @35904, buf1 @54336 (18432 ush each). fb-ends are all odd u -> feat
// aliases buf1 while gll-in-flight targets buf0.
__global__ __launch_bounds__(512)
void pot_kernel_ws(const int* __restrict__ input_char,
                   const int* __restrict__ input_script,
                   const float* __restrict__ char_emb,
                   const float* __restrict__ uscript_emb,
                   const float* __restrict__ dense_w,
                   const float* __restrict__ dense_b,
                   const float* __restrict__ left_b,
                   const float* __restrict__ right_b,
                   const float* __restrict__ cb1, const float* __restrict__ cb2,
                   const float* __restrict__ cb3, const float* __restrict__ cb4,
                   const float* __restrict__ cb5,
                   const ush* __restrict__ ws,
                   float* __restrict__ out_pot)
{
    __shared__ __align__(16) ush smem[77280];           // 154560 B
    ush* Ah     = smem;                                 // 132 x AP
    ush* Al     = smem + 17952;
    ush* feat_h = smem + 54336;                         // aliases buf1 (fb-end only)
    ush* feat_l = smem + 63040;
    float* uebt = (float*)(smem + 72768);               // 16 x 128 fp32
    float* dwue = (float*)(smem + 76864);               // 16 x 13 fp32

    const int tid  = threadIdx.x;
    const int lane = tid & 63;
    const int wid  = tid >> 6;
    const int tg   = wid >> 2;
    const int fg   = wid & 3;
    const int lr   = lane & 15;
    const int lq   = lane >> 4;
    const int bb   = blockIdx.x >> 2;
    const int t0   = (blockIdx.x & 3) << 7;

    // ---- issue gll for unit 0 into buf0 (overlaps A staging) ----
    {
        const char* g = (const char*)ws;
        char* l = (char*)(smem + 35904);
        #pragma unroll
        for (int i = 0; i < 5; ++i) {
            int idx = wid + (i << 3);
            if (i < 4 || wid < 4)
                __builtin_amdgcn_global_load_lds(
                    (const __attribute__((address_space(1))) void*)(g + idx*1024 + lane*16),
                    (__attribute__((address_space(3))) void*)(l + idx*1024 + lane*16), 16, 0, 0);
        }
    }

    // ---- stage A: emb rows t0-2 .. t0+129, fp32 -> bf16 hi/lo ----
    for (int i = tid; i < 132*16; i += 512) {
        int row = i >> 4, s = (i & 15) << 3;
        int t = t0 + row - 2;
        uint4 hv = {0,0,0,0}, lv = {0,0,0,0};
        if (t >= 0 && t < NT) {
            int ch = input_char[bb*NT + t];
            const float* src = char_emb + ch*128 + s;
            float4 x0 = *(const float4*)src;
            float4 x1 = *(const float4*)(src + 4);
            float fs[8] = {x0.x,x0.y,x0.z,x0.w,x1.x,x1.y,x1.z,x1.w};
            ush h[8], l[8];
            #pragma unroll
            for (int q = 0; q < 8; ++q) {
                h[q] = f2bf(fs[q]);
                l[q] = f2bf(fs[q] - bf2f(h[q]));
            }
            hv.x = h[0] | ((u32)h[1]<<16); hv.y = h[2] | ((u32)h[3]<<16);
            hv.z = h[4] | ((u32)h[5]<<16); hv.w = h[6] | ((u32)h[7]<<16);
            lv.x = l[0] | ((u32)l[1]<<16); lv.y = l[2] | ((u32)l[3]<<16);
            lv.z = l[4] | ((u32)l[5]<<16); lv.w = l[6] | ((u32)l[7]<<16);
        }
        *(uint4*)&Ah[row*AP + s] = hv;
        *(uint4*)&Al[row*AP + s] = lv;
    }
    // ---- stage uebt / dwue (fp32, exact) ----
    for (int i = tid; i < 2048; i += 512) {
        int uu = i >> 7, tl = i & 127;
        uebt[uu*128 + tl] = uscript_emb[input_script[bb*NT + t0 + tl]*16 + uu];
    }
    if (tid < 208) dwue[tid] = dense_w[640*13 + tid];
    __syncthreads();

    const float* cbs[5] = {cb1, cb2, cb3, cb4, cb5};

    f4v cacc[4][2];
    #pragma unroll
    for (int mt = 0; mt < 4; ++mt)
        #pragma unroll
        for (int nt = 0; nt < 2; ++nt) cacc[mt][nt] = (f4v){0.f,0.f,0.f,0.f};
    f4v dacc = (f4v){0.f,0.f,0.f,0.f};

    #pragma unroll 1
    for (int u = 0; u < 30; ++u) {
        int ut  = u >> 1, eh = u & 1;
        int fb  = ut<1?0: ut<3?1: ut<6?2: ut<10?3:4;
        int jj  = ut - fb*(fb+1)/2;
        int jsh = (2 - (fb >> 1)) + jj;

        // ---- issue gll for next unit into the other buffer ----
        if (u < 29) {
            const char* g = (const char*)ws + (u + 1)*36864;
            char* l = (char*)(smem + (((u + 1) & 1) ? 54336 : 35904));
            #pragma unroll
            for (int i = 0; i < 5; ++i) {
                int idx = wid + (i << 3);
                if (i < 4 || wid < 4)
                    __builtin_amdgcn_global_load_lds(
                        (const __attribute__((address_space(1))) void*)(g + idx*1024 + lane*16),
                        (__attribute__((address_space(3))) void*)(l + idx*1024 + lane*16), 16, 0, 0);
            }
        }

        // ---- conv MFMA: 48 per wave, from buf[u&1] ----
        const ush* Wh = smem + ((u & 1) ? 54336 : 35904);
        const ush* Wl = Wh + 9216;
        #pragma unroll
        for (int kk = 0; kk < 2; ++kk) {
            int ko = kk*32 + (lq << 3);
            s8v bh[2], bl[2];
            #pragma unroll
            for (int nt = 0; nt < 2; ++nt) {
                int frow = fg*32 + nt*16 + lr;
                bh[nt] = *(const s8v*)&Wh[frow*WP + ko];
                bl[nt] = *(const s8v*)&Wl[frow*WP + ko];
            }
            #pragma unroll
            for (int mt = 0; mt < 4; ++mt) {
                int row = tg*64 + mt*16 + lr + jsh;
                int ai  = row*AP + eh*64 + ko;
                s8v ah = *(const s8v*)&Ah[ai];
                s8v al = *(const s8v*)&Al[ai];
                #pragma unroll
                for (int nt = 0; nt < 2; ++nt) {
                    cacc[mt][nt] = __builtin_amdgcn_mfma_f32_16x16x32_bf16(ah, bh[nt], cacc[mt][nt], 0,0,0);
                    cacc[mt][nt] = __builtin_amdgcn_mfma_f32_16x16x32_bf16(ah, bl[nt], cacc[mt][nt], 0,0,0);
                    cacc[mt][nt] = __builtin_amdgcn_mfma_f32_16x16x32_bf16(al, bh[nt], cacc[mt][nt], 0,0,0);
                }
            }
        }

        // ---- end of an f-block (u odd): ReLU -> feat (aliases buf1) -> dense ----
        if (u == 1 || u == 5 || u == 11 || u == 19 || u == 29) {
            __syncthreads();   // all conv reads of buf1 done; safe to write feat
            float cbv0 = cbs[fb][fg*32 + lr];
            float cbv1 = cbs[fb][fg*32 + 16 + lr];

            #pragma unroll 1
            for (int h = 0; h < 2; ++h) {
                if (tg == h) {
                    #pragma unroll
                    for (int mt = 0; mt < 4; ++mt)
                        #pragma unroll
                        for (int nt = 0; nt < 2; ++nt)
                            #pragma unroll
                            for (int r = 0; r < 4; ++r) {
                                float v = fmaxf(cacc[mt][nt][r] + (nt ? cbv1 : cbv0), 0.f);
                                int rw = mt*16 + (lq << 2) + r;       // local t in half
                                int f  = fg*32 + nt*16 + lr;
                                ush hh = f2bf(v);
                                feat_h[rw*AP + f] = hh;
                                feat_l[rw*AP + f] = f2bf(v - bf2f(hh));
                            }
                }
                __syncthreads();
                if (tg == h) {
                    int trow = fg*16 + lr;                            // local t in half
                    #pragma unroll
                    for (int kf = 0; kf < 4; ++kf) {
                        int f0 = kf*32 + (lq << 3);
                        s8v a2h = *(const s8v*)&ws[DWT_H + fb*2048 + lr*128 + f0];
                        s8v a2l = *(const s8v*)&ws[DWT_L + fb*2048 + lr*128 + f0];
                        s8v b2h = *(const s8v*)&feat_h[trow*AP + f0];
                        s8v b2l = *(const s8v*)&feat_l[trow*AP + f0];
                        dacc = __builtin_amdgcn_mfma_f32_16x16x32_bf16(a2h, b2h, dacc, 0,0,0);
                        dacc = __builtin_amdgcn_mfma_f32_16x16x32_bf16(a2h, b2l, dacc, 0,0,0);
                        dacc = __builtin_amdgcn_mfma_f32_16x16x32_bf16(a2l, b2h, dacc, 0,0,0);
                    }
                    if (fb == 4) {
                        int tloc  = tg*64 + fg*16 + lr;
                        int tglob = t0 + tloc;
                        float pc[4];
                        #pragma unroll
                        for (int r = 0; r < 4; ++r) pc[r] = dacc[r];
                        #pragma unroll
                        for (int uu = 0; uu < 16; ++uu) {
                            float uv = uebt[uu*128 + tloc];
                            #pragma unroll
                            for (int r = 0; r < 4; ++r) {
                                int c = (lq << 2) + r;
                                if (c < 13) pc[r] = fmaf(uv, dwue[uu*13 + c], pc[r]);
                            }
                        }
                        #pragma unroll
                        for (int r = 0; r < 4; ++r) {
                            int c = (lq << 2) + r;
                            if (c < 13) {
                                float v = pc[r] + dense_b[c];
                                if (tglob == 0)    v += left_b[c];
                                if (tglob == NT-1) v += right_b[c];
                                out_pot[(bb*NT + tglob)*13 + c] = v;
                            }
                        }
                    }
                }
                __syncthreads();
            }
            #pragma unroll
            for (int mt = 0; mt < 4; ++mt)
                #pragma unroll
                for (int nt = 0; nt < 2; ++nt) cacc[mt][nt] = (f4v){0.f,0.f,0.f,0.f};
        } else {
            __syncthreads();   // drains this wave's gll (vmcnt) + publishes buffers
        }
    }
}

// ---- fallback pot (round-4 verbatim, used if ws_size too small) ----
__global__ __launch_bounds__(512)
void pot_kernel_fb(const int* __restrict__ input_char,
                   const int* __restrict__ input_script,
                   const float* __restrict__ char_emb,
                   const float* __restrict__ uscript_emb,
                   const float* __restrict__ dense_w,
                   const float* __restrict__ dense_b,
                   const float* __restrict__ left_b,
                   const float* __restrict__ right_b,
                   const float* __restrict__ cw1, const float* __restrict__ cb1,
                   const float* __restrict__ cw2, const float* __restrict__ cb2,
                   const float* __restrict__ cw3, const float* __restrict__ cb3,
                   const float* __restrict__ cw4, const float* __restrict__ cb4,
                   const float* __restrict__ cw5, const float* __restrict__ cb5,
                   float* __restrict__ out_pot)
{
    __shared__ __align__(16) ush smem[71744];
    ush* Ah     = smem;
    ush* Al     = smem + 17952;
    ush* Wh     = smem + 35904;
    ush* Wl     = smem + 45120;
    ush* feat_h = smem + 54336;
    ush* feat_l = smem + 63040;
    float* dwlds = (float*)(smem + 35904);
    float* dwue  = (float*)(smem + 39232);
    float* uebt  = (float*)(smem + 39648);

    const int tid  = threadIdx.x;
    const int lane = tid & 63;
    const int wid  = tid >> 6;
    const int tg   = wid >> 2;
    const int fg   = wid & 3;
    const int lr   = lane & 15;
    const int lq   = lane >> 4;
    const int bb   = blockIdx.x >> 2;
    const int t0   = (blockIdx.x & 3) << 7;

    for (int i = tid; i < 132*16; i += 512) {
        int row = i >> 4, s = (i & 15) << 3;
        int t = t0 + row - 2;
        uint4 hv = {0,0,0,0}, lv = {0,0,0,0};
        if (t >= 0 && t < NT) {
            int ch = input_char[bb*NT + t];
            const float* src = char_emb + ch*128 + s;
            float4 x0 = *(const float4*)src;
            float4 x1 = *(const float4*)(src + 4);
            float fs[8] = {x0.x,x0.y,x0.z,x0.w,x1.x,x1.y,x1.z,x1.w};
            ush h[8], l[8];
            #pragma unroll
            for (int q = 0; q < 8; ++q) {
                h[q] = f2bf(fs[q]);
                l[q] = f2bf(fs[q] - bf2f(h[q]));
            }
            hv.x = h[0] | ((u32)h[1]<<16); hv.y = h[2] | ((u32)h[3]<<16);
            hv.z = h[4] | ((u32)h[5]<<16); hv.w = h[6] | ((u32)h[7]<<16);
            lv.x = l[0] | ((u32)l[1]<<16); lv.y = l[2] | ((u32)l[3]<<16);
            lv.z = l[4] | ((u32)l[5]<<16); lv.w = l[6] | ((u32)l[7]<<16);
        }
        *(uint4*)&Ah[row*AP + s] = hv;
        *(uint4*)&Al[row*AP + s] = lv;
    }

    const float* cws[5] = {cw1, cw2, cw3, cw4, cw5};
    const float* cbs[5] = {cb1, cb2, cb3, cb4, cb5};

    f4v cacc[4][2];
    #pragma unroll
    for (int mt = 0; mt < 4; ++mt)
        #pragma unroll
        for (int nt = 0; nt < 2; ++nt) cacc[mt][nt] = (f4v){0.f,0.f,0.f,0.f};
    f4v dacc = (f4v){0.f,0.f,0.f,0.f};

    #pragma unroll 1
    for (int u = 0; u < 30; ++u) {
        int ut  = u >> 1, eh = u & 1;
        int fb  = ut<1?0: ut<3?1: ut<6?2: ut<10?3:4;
        int jj  = ut - fb*(fb+1)/2;
        int jsh = (2 - (fb >> 1)) + jj;
        const float* cw = cws[fb] + (jj*128 + eh*64)*128;

        __syncthreads();
        for (int g = tid; g < 1024; g += 512) {
            int f = g & 127, e8 = (g >> 7) << 3;
            float v[8];
            #pragma unroll
            for (int q = 0; q < 8; ++q) v[q] = cw[(e8 + q)*128 + f];
            ush h8[8], l8[8];
            #pragma unroll
            for (int q = 0; q < 8; ++q) {
                h8[q] = f2bf(v[q]);
                l8[q] = f2bf(v[q] - bf2f(h8[q]));
            }
            uint4 hv, lv;
            hv.x = h8[0] | ((u32)h8[1]<<16); hv.y = h8[2] | ((u32)h8[3]<<16);
            hv.z = h8[4] | ((u32)h8[5]<<16); hv.w = h8[6] | ((u32)h8[7]<<16);
            lv.x = l8[0] | ((u32)l8[1]<<16); lv.y = l8[2] | ((u32)l8[3]<<16);
            lv.z = l8[4] | ((u32)l8[5]<<16); lv.w = l8[6] | ((u32)l8[7]<<16);
            *(uint4*)&Wh[f*WP + e8] = hv;
            *(uint4*)&Wl[f*WP + e8] = lv;
        }
        __syncthreads();

        #pragma unroll
        for (int kk = 0; kk < 2; ++kk) {
            int ko = kk*32 + (lq << 3);
            s8v bh[2], bl[2];
            #pragma unroll
            for (int nt = 0; nt < 2; ++nt) {
                int frow = fg*32 + nt*16 + lr;
                bh[nt] = *(const s8v*)&Wh[frow*WP + ko];
                bl[nt] = *(const s8v*)&Wl[frow*WP + ko];
            }
            #pragma unroll
            for (int mt = 0; mt < 4; ++mt) {
                int row = tg*64 + mt*16 + lr + jsh;
                int ai  = row*AP + eh*64 + ko;
                s8v ah = *(const s8v*)&Ah[ai];
                s8v al = *(const s8v*)&Al[ai];
                #pragma unroll
                for (int nt = 0; nt < 2; ++nt) {
                    cacc[mt][nt] = __builtin_amdgcn_mfma_f32_16x16x32_bf16(ah, bh[nt], cacc[mt][nt], 0,0,0);
                    cacc[mt][nt] = __builtin_amdgcn_mfma_f32_16x16x32_bf16(ah, bl[nt], cacc[mt][nt], 0,0,0);
                    cacc[mt][nt] = __builtin_amdgcn_mfma_f32_16x16x32_bf16(al, bh[nt], cacc[mt][nt], 0,0,0);
                }
            }
        }

        if (u == 1 || u == 5 || u == 11 || u == 19 || u == 29) {
            __syncthreads();
            for (int i = tid; i < 128*13; i += 512)
                dwlds[i] = dense_w[fb*128*13 + i];
            if (fb == 4) {
                for (int i = tid; i < 16*13; i += 512)
                    dwue[i] = dense_w[640*13 + i];
                for (int i = tid; i < 2048; i += 512) {
                    int uu = i >> 7, tl = i & 127;
                    uebt[uu*128 + tl] = uscript_emb[input_script[bb*NT + t0 + tl]*16 + uu];
                }
            }
            __syncthreads();

            float cbv0 = cbs[fb][fg*32 + lr];
            float cbv1 = cbs[fb][fg*32 + 16 + lr];

            #pragma unroll 1
            for (int h = 0; h < 2; ++h) {
                if (tg == h) {
                    #pragma unroll
                    for (int mt = 0; mt < 4; ++mt)
                        #pragma unroll
                        for (int nt = 0; nt < 2; ++nt)
                            #pragma unroll
                            for (int r = 0; r < 4; ++r) {
                                float v = fmaxf(cacc[mt][nt][r] + (nt ? cbv1 : cbv0), 0.f);
                                int rw = mt*16 + (lq << 2) + r;
                                int f  = fg*32 + nt*16 + lr;
                                ush hh = f2bf(v);
                                feat_h[rw*AP + f] = hh;
                                feat_l[rw*AP + f] = f2bf(v - bf2f(hh));
                            }
                }
                __syncthreads();
                if (tg == h) {
                    int trow = fg*16 + lr;
                    #pragma unroll
                    for (int kf = 0; kf < 4; ++kf) {
                        int f0 = kf*32 + (lq << 3);
                        float dv[8];
                        #pragma unroll
                        for (int q = 0; q < 8; ++q) dv[q] = dwlds[(f0 + q)*13 + lr];
                        s8v a2h, a2l;
                        #pragma unroll
                        for (int q = 0; q < 8; ++q) {
                            ush hh = f2bf(dv[q]);
                            a2h[q] = (short)hh;
                            a2l[q] = (short)f2bf(dv[q] - bf2f(hh));
                        }
                        s8v b2h = *(const s8v*)&feat_h[trow*AP + f0];
                        s8v b2l = *(const s8v*)&feat_l[trow*AP + f0];
                        dacc = __builtin_amdgcn_mfma_f32_16x16x32_bf16(a2h, b2h, dacc, 0,0,0);
                        dacc = __builtin_amdgcn_mfma_f32_16x16x32_bf16(a2h, b2l, dacc, 0,0,0);
                        dacc = __builtin_amdgcn_mfma_f32_16x16x32_bf16(a2l, b2h, dacc, 0,0,0);
                    }
                    if (fb == 4) {
                        int tloc  = tg*64 + fg*16 + lr;
                        int tglob = t0 + tloc;
                        float pc[4];
                        #pragma unroll
                        for (int r = 0; r < 4; ++r) pc[r] = dacc[r];
                        #pragma unroll
                        for (int uu = 0; uu < 16; ++uu) {
                            float uv = uebt[uu*128 + tloc];
                            #pragma unroll
                            for (int r = 0; r < 4; ++r) {
                                int c = (lq << 2) + r;
                                if (c < 13) pc[r] = fmaf(uv, dwue[uu*13 + c], pc[r]);
                            }
                        }
                        #pragma unroll
                        for (int r = 0; r < 4; ++r) {
                            int c = (lq << 2) + r;
                            if (c < 13) {
                                float v = pc[r] + dense_b[c];
                                if (tglob == 0)    v += left_b[c];
                                if (tglob == NT-1) v += right_b[c];
                                out_pot[(bb*NT + tglob)*13 + c] = v;
                            }
                        }
                    }
                }
                __syncthreads();
            }
            #pragma unroll
            for (int mt = 0; mt < 4; ++mt)
                #pragma unroll
                for (int nt = 0; nt < 2; ++nt) cacc[mt][nt] = (f4v){0.f,0.f,0.f,0.f};
        }
    }
}

// ---------------- viterbi (round-2 version, proven) ----------------
__global__ __launch_bounds__(256)
void viterbi_kernel(const float* __restrict__ pot,
                    const float* __restrict__ trans,
                    float* __restrict__ out_dec,
                    float* __restrict__ out_seq,
                    float* __restrict__ out_trans)
{
    __shared__ __align__(16) float s_lds[NT * NC];
    __shared__ float t_lds[NC * NC];
    __shared__ unsigned char path_lds[16 * 13 * 32];
    __shared__ unsigned char entry_lds[16 * 13];
    __shared__ int chunk_e[16];

    const int b   = blockIdx.x;
    const int tid = threadIdx.x;

    {
        const float4* src = reinterpret_cast<const float4*>(pot + b * NT * NC);
        float4* dst = reinterpret_cast<float4*>(s_lds);
        for (int i = tid; i < NT * NC / 4; i += 256) dst[i] = src[i];
        for (int i = tid; i < NC * NC; i += 256) t_lds[i] = trans[i];
    }
    __syncthreads();

    if (tid < 64) {
        const int c = tid;
        const bool act = c < NC;
        float tc[13];
        #pragma unroll
        for (int p = 0; p < NC; ++p) tc[p] = t_lds[p * NC + (act ? c : 0)];
        float s = act ? s_lds[c] : -1e30f;

        for (int t = 1; t < NT; ++t) {
            float v[13];
            #pragma unroll
            for (int p = 0; p < NC; ++p) v[p] = __shfl(s, p) + tc[p];
            float m0 = fmaxf(fmaxf(v[0], v[1]), fmaxf(v[2], v[3]));
            float m1 = fmaxf(fmaxf(v[4], v[5]), fmaxf(v[6], v[7]));
            float m2 = fmaxf(fmaxf(v[8], v[9]), fmaxf(v[10], v[11]));
            float best = fmaxf(fmaxf(m0, m1), fmaxf(m2, v[12]));
            float pv = act ? s_lds[t * NC + c] : 0.f;
            s = best + pv;
            if (act) s_lds[t * NC + c] = s;
        }
    }
    __syncthreads();

    if (tid < 16 * 13) {
        const int chunk = tid / 13;
        const int e     = tid - chunk * 13;
        unsigned char* path = &path_lds[(chunk * 13 + e) * 32];
        int cur = e;
        path[31] = (unsigned char)e;
        for (int tl = 31; tl >= 1; --tl) {
            const float* srow = &s_lds[(chunk * 32 + tl - 1) * NC];
            float best = -1e30f; int bi = 0;
            #pragma unroll
            for (int p = 0; p < NC; ++p) {
                float v = srow[p] + t_lds[p * NC + cur];
                if (v > best) { best = v; bi = p; }   // first-max (jnp.argmax)
            }
            cur = bi;
            path[tl - 1] = (unsigned char)cur;
        }
        if (chunk > 0) {
            const float* srow = &s_lds[(chunk * 32 - 1) * NC];
            float best = -1e30f; int bi = 0;
            #pragma unroll
            for (int p = 0; p < NC; ++p) {
                float v = srow[p] + t_lds[p * NC + cur];
                if (v > best) { best = v; bi = p; }
            }
            entry_lds[chunk * 13 + e] = (unsigned char)bi;
        }
    }
    __syncthreads();

    if (tid == 0) {
        float best = -1e30f; int last = 0;
        for (int c = 0; c < NC; ++c) {
            float v = s_lds[(NT - 1) * NC + c];
            if (v > best) { best = v; last = c; }
        }
        chunk_e[15] = last;
        for (int i = 15; i >= 1; --i)
            chunk_e[i - 1] = entry_lds[i * 13 + chunk_e[i]];
    }
    __syncthreads();

    float* dec = out_dec + b * NT;
    for (int t = tid; t < NT; t += 256) {
        int ck = t >> 5;
        dec[t] = (float)path_lds[(ck * 13 + chunk_e[ck]) * 32 + (t & 31)];
    }
    if (tid == 0) out_seq[b] = (float)NT;
    if (b == 0) {
        for (int i = tid; i < NC * NC; i += 256) out_trans[i] = trans[i];
    }
}

extern "C" void kernel_launch(void* const* d_in, const int* in_sizes, int n_in,
                              void* d_out, int out_size, void* d_ws, size_t ws_size,
                              hipStream_t stream) {
    const int*   input_char   = (const int*)d_in[0];
    const int*   input_script = (const int*)d_in[1];
    const float* char_emb     = (const float*)d_in[3];
    const float* uscript_emb  = (const float*)d_in[4];
    const float* dense_w      = (const float*)d_in[5];
    const float* dense_b      = (const float*)d_in[6];
    const float* trans        = (const float*)d_in[7];
    const float* left_b       = (const float*)d_in[8];
    const float* right_b      = (const float*)d_in[9];
    const float* cw1 = (const float*)d_in[10];
    const float* cb1 = (const float*)d_in[11];
    const float* cw2 = (const float*)d_in[12];
    const float* cb2 = (const float*)d_in[13];
    const float* cw3 = (const float*)d_in[14];
    const float* cb3 = (const float*)d_in[15];
    const float* cw4 = (const float*)d_in[16];
    const float* cb4 = (const float*)d_in[17];
    const float* cw5 = (const float*)d_in[18];
    const float* cb5 = (const float*)d_in[19];

    float* out       = (float*)d_out;
    float* out_dec   = out;                       // [B,T] decoded tags (as float)
    float* out_pot   = out + NB * NT;             // [B,T,C]
    float* out_seq   = out_pot + NB * NT * NC;    // [B]
    float* out_trans = out_seq + NB;              // [C,C]

    if (ws_size >= (size_t)WS_NEED) {
        hipLaunchKernelGGL(prep_kernel, dim3(35), dim3(512), 0, stream,
                           cw1, cw2, cw3, cw4, cw5, dense_w, (ush*)d_ws);
        hipLaunchKernelGGL(pot_kernel_ws, dim3(256), dim3(512), 0, stream,
                           input_char, input_script, char_emb, uscript_emb,
                           dense_w, dense_b, left_b, right_b,
                           cb1, cb2, cb3, cb4, cb5,
                           (const ush*)d_ws, out_pot);
    } else {
        hipLaunchKernelGGL(pot_kernel_fb, dim3(256), dim3(512), 0, stream,
                           input_char, input_script, char_emb, uscript_emb,
                           dense_w, dense_b, left_b, right_b,
                           cw1, cb1, cw2, cb2, cw3, cb3, cw4, cb4, cw5, cb5,
                           out_pot);
    }

    hipLaunchKernelGGL(viterbi_kernel, dim3(NB), dim3(256), 0, stream,
                       out_pot, trans, out_dec, out_seq, out_trans);
}

// Round 7
// 157.377 us; speedup vs baseline: 1.4656x; 1.0380x over previous
//
#include <hip/hip_runtime.h>

#define NB 64
#define NT 512
#define NC 13
#define AP 136    // A row stride (ush)
#define WP 72     // W row stride (ush)
#define PT 516    // transposed-pot row stride (floats)
#define USTRIDE 18432            // ush per W unit (hi 9216 + lo 9216) = 36864 B
#define DWT_H   552960           // 30*18432
#define DWT_L   563200           // DWT_H + 5*2048
#define WS_NEED 1146880          // bytes

typedef short s8v __attribute__((ext_vector_type(8)));
typedef float f4v __attribute__((ext_vector_type(4)));
typedef unsigned short ush;
typedef unsigned int u32;

__device__ __forceinline__ ush f2bf(float f){
    union { float f; u32 u; } v; v.f = f;
    u32 r = v.u + 0x7fffu + ((v.u >> 16) & 1u);
    return (ush)(r >> 16);
}
__device__ __forceinline__ float bf2f(ush h){
    union { u32 u; float f; } v; v.u = ((u32)h) << 16; return v.f;
}

// ---- prep: pre-split W (+ dwT) into ws in pot's exact padded LDS layout ----
__global__ __launch_bounds__(512)
void prep_kernel(const float* __restrict__ cw1, const float* __restrict__ cw2,
                 const float* __restrict__ cw3, const float* __restrict__ cw4,
                 const float* __restrict__ cw5, const float* __restrict__ dense_w,
                 ush* __restrict__ ws)
{
    int bx = blockIdx.x, tid = threadIdx.x;
    if (bx < 30) {
        int u = bx, ut = u >> 1, eh = u & 1;
        int fb = ut<1?0: ut<3?1: ut<6?2: ut<10?3:4;
        int jj = ut - fb*(fb+1)/2;
        const float* cw = fb==0?cw1: fb==1?cw2: fb==2?cw3: fb==3?cw4: cw5;
        #pragma unroll
        for (int it = 0; it < 2; ++it) {
            int g = it*512 + tid;            // 0..1023
            int f = g & 127;
            int e8 = (g >> 7) << 3;          // 0..56
            float v[8];
            #pragma unroll
            for (int q = 0; q < 8; ++q)
                v[q] = cw[(jj*128 + eh*64 + e8 + q)*128 + f];
            ush h8[8], l8[8];
            #pragma unroll
            for (int q = 0; q < 8; ++q) {
                h8[q] = f2bf(v[q]);
                l8[q] = f2bf(v[q] - bf2f(h8[q]));
            }
            uint4 hv, lv;
            hv.x = h8[0] | ((u32)h8[1]<<16); hv.y = h8[2] | ((u32)h8[3]<<16);
            hv.z = h8[4] | ((u32)h8[5]<<16); hv.w = h8[6] | ((u32)h8[7]<<16);
            lv.x = l8[0] | ((u32)l8[1]<<16); lv.y = l8[2] | ((u32)l8[3]<<16);
            lv.z = l8[4] | ((u32)l8[5]<<16); lv.w = l8[6] | ((u32)l8[7]<<16);
            *(uint4*)&ws[u*USTRIDE + f*WP + e8]        = hv;
            *(uint4*)&ws[u*USTRIDE + 9216 + f*WP + e8] = lv;
        }
    } else {
        int fb = bx - 30;
        #pragma unroll
        for (int it = 0; it < 4; ++it) {
            int idx = it*512 + tid;          // 0..2047 = c*128+f
            int c = idx >> 7, f = idx & 127;
            float v = (c < 13) ? dense_w[(fb*128 + f)*13 + c] : 0.f;
            ush hi = f2bf(v);
            ws[DWT_H + fb*2048 + idx] = hi;
            ws[DWT_L + fb*2048 + idx] = f2bf(v - bf2f(hi));
        }
    }
}

// ---- pot v6: gll double-buffered W staging (static LDS) — unchanged ----
__global__ __launch_bounds__(512)
void pot_kernel_ws(const int* __restrict__ input_char,
                   const int* __restrict__ input_script,
                   const float* __restrict__ char_emb,
                   const float* __restrict__ uscript_emb,
                   const float* __restrict__ dense_w,
                   const float* __restrict__ dense_b,
                   const float* __restrict__ left_b,
                   const float* __restrict__ right_b,
                   const float* __restrict__ cb1, const float* __restrict__ cb2,
                   const float* __restrict__ cb3, const float* __restrict__ cb4,
                   const float* __restrict__ cb5,
                   const ush* __restrict__ ws,
                   float* __restrict__ out_pot)
{
    __shared__ __align__(16) ush smem[77280];           // 154560 B
    ush* Ah     = smem;                                 // 132 x AP
    ush* Al     = smem + 17952;
    ush* feat_h = smem + 54336;                         // aliases buf1 (fb-end only)
    ush* feat_l = smem + 63040;
    float* uebt = (float*)(smem + 72768);               // 16 x 128 fp32
    float* dwue = (float*)(smem + 76864);               // 16 x 13 fp32

    const int tid  = threadIdx.x;
    const int lane = tid & 63;
    const int wid  = tid >> 6;
    const int tg   = wid >> 2;
    const int fg   = wid & 3;
    const int lr   = lane & 15;
    const int lq   = lane >> 4;
    const int bb   = blockIdx.x >> 2;
    const int t0   = (blockIdx.x & 3) << 7;

    // ---- issue gll for unit 0 into buf0 (overlaps A staging) ----
    {
        const char* g = (const char*)ws;
        char* l = (char*)(smem + 35904);
        #pragma unroll
        for (int i = 0; i < 5; ++i) {
            int idx = wid + (i << 3);
            if (i < 4 || wid < 4)
                __builtin_amdgcn_global_load_lds(
                    (const __attribute__((address_space(1))) void*)(g + idx*1024 + lane*16),
                    (__attribute__((address_space(3))) void*)(l + idx*1024 + lane*16), 16, 0, 0);
        }
    }

    // ---- stage A: emb rows t0-2 .. t0+129, fp32 -> bf16 hi/lo ----
    for (int i = tid; i < 132*16; i += 512) {
        int row = i >> 4, s = (i & 15) << 3;
        int t = t0 + row - 2;
        uint4 hv = {0,0,0,0}, lv = {0,0,0,0};
        if (t >= 0 && t < NT) {
            int ch = input_char[bb*NT + t];
            const float* src = char_emb + ch*128 + s;
            float4 x0 = *(const float4*)src;
            float4 x1 = *(const float4*)(src + 4);
            float fs[8] = {x0.x,x0.y,x0.z,x0.w,x1.x,x1.y,x1.z,x1.w};
            ush h[8], l[8];
            #pragma unroll
            for (int q = 0; q < 8; ++q) {
                h[q] = f2bf(fs[q]);
                l[q] = f2bf(fs[q] - bf2f(h[q]));
            }
            hv.x = h[0] | ((u32)h[1]<<16); hv.y = h[2] | ((u32)h[3]<<16);
            hv.z = h[4] | ((u32)h[5]<<16); hv.w = h[6] | ((u32)h[7]<<16);
            lv.x = l[0] | ((u32)l[1]<<16); lv.y = l[2] | ((u32)l[3]<<16);
            lv.z = l[4] | ((u32)l[5]<<16); lv.w = l[6] | ((u32)l[7]<<16);
        }
        *(uint4*)&Ah[row*AP + s] = hv;
        *(uint4*)&Al[row*AP + s] = lv;
    }
    // ---- stage uebt / dwue (fp32, exact) ----
    for (int i = tid; i < 2048; i += 512) {
        int uu = i >> 7, tl = i & 127;
        uebt[uu*128 + tl] = uscript_emb[input_script[bb*NT + t0 + tl]*16 + uu];
    }
    if (tid < 208) dwue[tid] = dense_w[640*13 + tid];
    __syncthreads();

    const float* cbs[5] = {cb1, cb2, cb3, cb4, cb5};

    f4v cacc[4][2];
    #pragma unroll
    for (int mt = 0; mt < 4; ++mt)
        #pragma unroll
        for (int nt = 0; nt < 2; ++nt) cacc[mt][nt] = (f4v){0.f,0.f,0.f,0.f};
    f4v dacc = (f4v){0.f,0.f,0.f,0.f};

    #pragma unroll 1
    for (int u = 0; u < 30; ++u) {
        int ut  = u >> 1, eh = u & 1;
        int fb  = ut<1?0: ut<3?1: ut<6?2: ut<10?3:4;
        int jj  = ut - fb*(fb+1)/2;
        int jsh = (2 - (fb >> 1)) + jj;

        // ---- issue gll for next unit into the other buffer ----
        if (u < 29) {
            const char* g = (const char*)ws + (u + 1)*36864;
            char* l = (char*)(smem + (((u + 1) & 1) ? 54336 : 35904));
            #pragma unroll
            for (int i = 0; i < 5; ++i) {
                int idx = wid + (i << 3);
                if (i < 4 || wid < 4)
                    __builtin_amdgcn_global_load_lds(
                        (const __attribute__((address_space(1))) void*)(g + idx*1024 + lane*16),
                        (__attribute__((address_space(3))) void*)(l + idx*1024 + lane*16), 16, 0, 0);
            }
        }

        // ---- conv MFMA: 48 per wave, from buf[u&1] ----
        const ush* Wh = smem + ((u & 1) ? 54336 : 35904);
        const ush* Wl = Wh + 9216;
        #pragma unroll
        for (int kk = 0; kk < 2; ++kk) {
            int ko = kk*32 + (lq << 3);
            s8v bh[2], bl[2];
            #pragma unroll
            for (int nt = 0; nt < 2; ++nt) {
                int frow = fg*32 + nt*16 + lr;
                bh[nt] = *(const s8v*)&Wh[frow*WP + ko];
                bl[nt] = *(const s8v*)&Wl[frow*WP + ko];
            }
            #pragma unroll
            for (int mt = 0; mt < 4; ++mt) {
                int row = tg*64 + mt*16 + lr + jsh;
                int ai  = row*AP + eh*64 + ko;
                s8v ah = *(const s8v*)&Ah[ai];
                s8v al = *(const s8v*)&Al[ai];
                #pragma unroll
                for (int nt = 0; nt < 2; ++nt) {
                    cacc[mt][nt] = __builtin_amdgcn_mfma_f32_16x16x32_bf16(ah, bh[nt], cacc[mt][nt], 0,0,0);
                    cacc[mt][nt] = __builtin_amdgcn_mfma_f32_16x16x32_bf16(ah, bl[nt], cacc[mt][nt], 0,0,0);
                    cacc[mt][nt] = __builtin_amdgcn_mfma_f32_16x16x32_bf16(al, bh[nt], cacc[mt][nt], 0,0,0);
                }
            }
        }

        // ---- end of an f-block (u odd): ReLU -> feat (aliases buf1) -> dense ----
        if (u == 1 || u == 5 || u == 11 || u == 19 || u == 29) {
            __syncthreads();   // all conv reads of buf1 done; safe to write feat
            float cbv0 = cbs[fb][fg*32 + lr];
            float cbv1 = cbs[fb][fg*32 + 16 + lr];

            #pragma unroll 1
            for (int h = 0; h < 2; ++h) {
                if (tg == h) {
                    #pragma unroll
                    for (int mt = 0; mt < 4; ++mt)
                        #pragma unroll
                        for (int nt = 0; nt < 2; ++nt)
                            #pragma unroll
                            for (int r = 0; r < 4; ++r) {
                                float v = fmaxf(cacc[mt][nt][r] + (nt ? cbv1 : cbv0), 0.f);
                                int rw = mt*16 + (lq << 2) + r;       // local t in half
                                int f  = fg*32 + nt*16 + lr;
                                ush hh = f2bf(v);
                                feat_h[rw*AP + f] = hh;
                                feat_l[rw*AP + f] = f2bf(v - bf2f(hh));
                            }
                }
                __syncthreads();
                if (tg == h) {
                    int trow = fg*16 + lr;                            // local t in half
                    #pragma unroll
                    for (int kf = 0; kf < 4; ++kf) {
                        int f0 = kf*32 + (lq << 3);
                        s8v a2h = *(const s8v*)&ws[DWT_H + fb*2048 + lr*128 + f0];
                        s8v a2l = *(const s8v*)&ws[DWT_L + fb*2048 + lr*128 + f0];
                        s8v b2h = *(const s8v*)&feat_h[trow*AP + f0];
                        s8v b2l = *(const s8v*)&feat_l[trow*AP + f0];
                        dacc = __builtin_amdgcn_mfma_f32_16x16x32_bf16(a2h, b2h, dacc, 0,0,0);
                        dacc = __builtin_amdgcn_mfma_f32_16x16x32_bf16(a2h, b2l, dacc, 0,0,0);
                        dacc = __builtin_amdgcn_mfma_f32_16x16x32_bf16(a2l, b2h, dacc, 0,0,0);
                    }
                    if (fb == 4) {
                        int tloc  = tg*64 + fg*16 + lr;
                        int tglob = t0 + tloc;
                        float pc[4];
                        #pragma unroll
                        for (int r = 0; r < 4; ++r) pc[r] = dacc[r];
                        #pragma unroll
                        for (int uu = 0; uu < 16; ++uu) {
                            float uv = uebt[uu*128 + tloc];
                            #pragma unroll
                            for (int r = 0; r < 4; ++r) {
                                int c = (lq << 2) + r;
                                if (c < 13) pc[r] = fmaf(uv, dwue[uu*13 + c], pc[r]);
                            }
                        }
                        #pragma unroll
                        for (int r = 0; r < 4; ++r) {
                            int c = (lq << 2) + r;
                            if (c < 13) {
                                float v = pc[r] + dense_b[c];
                                if (tglob == 0)    v += left_b[c];
                                if (tglob == NT-1) v += right_b[c];
                                out_pot[(bb*NT + tglob)*13 + c] = v;
                            }
                        }
                    }
                }
                __syncthreads();
            }
            #pragma unroll
            for (int mt = 0; mt < 4; ++mt)
                #pragma unroll
                for (int nt = 0; nt < 2; ++nt) cacc[mt][nt] = (f4v){0.f,0.f,0.f,0.f};
        } else {
            __syncthreads();   // drains this wave's gll (vmcnt) + publishes buffers
        }
    }
}

// ---- fallback pot (round-4 verbatim, used if ws_size too small) ----
__global__ __launch_bounds__(512)
void pot_kernel_fb(const int* __restrict__ input_char,
                   const int* __restrict__ input_script,
                   const float* __restrict__ char_emb,
                   const float* __restrict__ uscript_emb,
                   const float* __restrict__ dense_w,
                   const float* __restrict__ dense_b,
                   const float* __restrict__ left_b,
                   const float* __restrict__ right_b,
                   const float* __restrict__ cw1, const float* __restrict__ cb1,
                   const float* __restrict__ cw2, const float* __restrict__ cb2,
                   const float* __restrict__ cw3, const float* __restrict__ cb3,
                   const float* __restrict__ cw4, const float* __restrict__ cb4,
                   const float* __restrict__ cw5, const float* __restrict__ cb5,
                   float* __restrict__ out_pot)
{
    __shared__ __align__(16) ush smem[71744];
    ush* Ah     = smem;
    ush* Al     = smem + 17952;
    ush* Wh     = smem + 35904;
    ush* Wl     = smem + 45120;
    ush* feat_h = smem + 54336;
    ush* feat_l = smem + 63040;
    float* dwlds = (float*)(smem + 35904);
    float* dwue  = (float*)(smem + 39232);
    float* uebt  = (float*)(smem + 39648);

    const int tid  = threadIdx.x;
    const int lane = tid & 63;
    const int wid  = tid >> 6;
    const int tg   = wid >> 2;
    const int fg   = wid & 3;
    const int lr   = lane & 15;
    const int lq   = lane >> 4;
    const int bb   = blockIdx.x >> 2;
    const int t0   = (blockIdx.x & 3) << 7;

    for (int i = tid; i < 132*16; i += 512) {
        int row = i >> 4, s = (i & 15) << 3;
        int t = t0 + row - 2;
        uint4 hv = {0,0,0,0}, lv = {0,0,0,0};
        if (t >= 0 && t < NT) {
            int ch = input_char[bb*NT + t];
            const float* src = char_emb + ch*128 + s;
            float4 x0 = *(const float4*)src;
            float4 x1 = *(const float4*)(src + 4);
            float fs[8] = {x0.x,x0.y,x0.z,x0.w,x1.x,x1.y,x1.z,x1.w};
            ush h[8], l[8];
            #pragma unroll
            for (int q = 0; q < 8; ++q) {
                h[q] = f2bf(fs[q]);
                l[q] = f2bf(fs[q] - bf2f(h[q]));
            }
            hv.x = h[0] | ((u32)h[1]<<16); hv.y = h[2] | ((u32)h[3]<<16);
            hv.z = h[4] | ((u32)h[5]<<16); hv.w = h[6] | ((u32)h[7]<<16);
            lv.x = l[0] | ((u32)l[1]<<16); lv.y = l[2] | ((u32)l[3]<<16);
            lv.z = l[4] | ((u32)l[5]<<16); lv.w = l[6] | ((u32)l[7]<<16);
        }
        *(uint4*)&Ah[row*AP + s] = hv;
        *(uint4*)&Al[row*AP + s] = lv;
    }

    const float* cws[5] = {cw1, cw2, cw3, cw4, cw5};
    const float* cbs[5] = {cb1, cb2, cb3, cb4, cb5};

    f4v cacc[4][2];
    #pragma unroll
    for (int mt = 0; mt < 4; ++mt)
        #pragma unroll
        for (int nt = 0; nt < 2; ++nt) cacc[mt][nt] = (f4v){0.f,0.f,0.f,0.f};
    f4v dacc = (f4v){0.f,0.f,0.f,0.f};

    #pragma unroll 1
    for (int u = 0; u < 30; ++u) {
        int ut  = u >> 1, eh = u & 1;
        int fb  = ut<1?0: ut<3?1: ut<6?2: ut<10?3:4;
        int jj  = ut - fb*(fb+1)/2;
        int jsh = (2 - (fb >> 1)) + jj;
        const float* cw = cws[fb] + (jj*128 + eh*64)*128;

        __syncthreads();
        for (int g = tid; g < 1024; g += 512) {
            int f = g & 127, e8 = (g >> 7) << 3;
            float v[8];
            #pragma unroll
            for (int q = 0; q < 8; ++q) v[q] = cw[(e8 + q)*128 + f];
            ush h8[8], l8[8];
            #pragma unroll
            for (int q = 0; q < 8; ++q) {
                h8[q] = f2bf(v[q]);
                l8[q] = f2bf(v[q] - bf2f(h8[q]));
            }
            uint4 hv, lv;
            hv.x = h8[0] | ((u32)h8[1]<<16); hv.y = h8[2] | ((u32)h8[3]<<16);
            hv.z = h8[4] | ((u32)h8[5]<<16); hv.w = h8[6] | ((u32)h8[7]<<16);
            lv.x = l8[0] | ((u32)l8[1]<<16); lv.y = l8[2] | ((u32)l8[3]<<16);
            lv.z = l8[4] | ((u32)l8[5]<<16); lv.w = l8[6] | ((u32)l8[7]<<16);
            *(uint4*)&Wh[f*WP + e8] = hv;
            *(uint4*)&Wl[f*WP + e8] = lv;
        }
        __syncthreads();

        #pragma unroll
        for (int kk = 0; kk < 2; ++kk) {
            int ko = kk*32 + (lq << 3);
            s8v bh[2], bl[2];
            #pragma unroll
            for (int nt = 0; nt < 2; ++nt) {
                int frow = fg*32 + nt*16 + lr;
                bh[nt] = *(const s8v*)&Wh[frow*WP + ko];
                bl[nt] = *(const s8v*)&Wl[frow*WP + ko];
            }
            #pragma unroll
            for (int mt = 0; mt < 4; ++mt) {
                int row = tg*64 + mt*16 + lr + jsh;
                int ai  = row*AP + eh*64 + ko;
                s8v ah = *(const s8v*)&Ah[ai];
                s8v al = *(const s8v*)&Al[ai];
                #pragma unroll
                for (int nt = 0; nt < 2; ++nt) {
                    cacc[mt][nt] = __builtin_amdgcn_mfma_f32_16x16x32_bf16(ah, bh[nt], cacc[mt][nt], 0,0,0);
                    cacc[mt][nt] = __builtin_amdgcn_mfma_f32_16x16x32_bf16(ah, bl[nt], cacc[mt][nt], 0,0,0);
                    cacc[mt][nt] = __builtin_amdgcn_mfma_f32_16x16x32_bf16(al, bh[nt], cacc[mt][nt], 0,0,0);
                }
            }
        }

        if (u == 1 || u == 5 || u == 11 || u == 19 || u == 29) {
            __syncthreads();
            for (int i = tid; i < 128*13; i += 512)
                dwlds[i] = dense_w[fb*128*13 + i];
            if (fb == 4) {
                for (int i = tid; i < 16*13; i += 512)
                    dwue[i] = dense_w[640*13 + i];
                for (int i = tid; i < 2048; i += 512) {
                    int uu = i >> 7, tl = i & 127;
                    uebt[uu*128 + tl] = uscript_emb[input_script[bb*NT + t0 + tl]*16 + uu];
                }
            }
            __syncthreads();

            float cbv0 = cbs[fb][fg*32 + lr];
            float cbv1 = cbs[fb][fg*32 + 16 + lr];

            #pragma unroll 1
            for (int h = 0; h < 2; ++h) {
                if (tg == h) {
                    #pragma unroll
                    for (int mt = 0; mt < 4; ++mt)
                        #pragma unroll
                        for (int nt = 0; nt < 2; ++nt)
                            #pragma unroll
                            for (int r = 0; r < 4; ++r) {
                                float v = fmaxf(cacc[mt][nt][r] + (nt ? cbv1 : cbv0), 0.f);
                                int rw = mt*16 + (lq << 2) + r;
                                int f  = fg*32 + nt*16 + lr;
                                ush hh = f2bf(v);
                                feat_h[rw*AP + f] = hh;
                                feat_l[rw*AP + f] = f2bf(v - bf2f(hh));
                            }
                }
                __syncthreads();
                if (tg == h) {
                    int trow = fg*16 + lr;
                    #pragma unroll
                    for (int kf = 0; kf < 4; ++kf) {
                        int f0 = kf*32 + (lq << 3);
                        float dv[8];
                        #pragma unroll
                        for (int q = 0; q < 8; ++q) dv[q] = dwlds[(f0 + q)*13 + lr];
                        s8v a2h, a2l;
                        #pragma unroll
                        for (int q = 0; q < 8; ++q) {
                            ush hh = f2bf(dv[q]);
                            a2h[q] = (short)hh;
                            a2l[q] = (short)f2bf(dv[q] - bf2f(hh));
                        }
                        s8v b2h = *(const s8v*)&feat_h[trow*AP + f0];
                        s8v b2l = *(const s8v*)&feat_l[trow*AP + f0];
                        dacc = __builtin_amdgcn_mfma_f32_16x16x32_bf16(a2h, b2h, dacc, 0,0,0);
                        dacc = __builtin_amdgcn_mfma_f32_16x16x32_bf16(a2h, b2l, dacc, 0,0,0);
                        dacc = __builtin_amdgcn_mfma_f32_16x16x32_bf16(a2l, b2h, dacc, 0,0,0);
                    }
                    if (fb == 4) {
                        int tloc  = tg*64 + fg*16 + lr;
                        int tglob = t0 + tloc;
                        float pc[4];
                        #pragma unroll
                        for (int r = 0; r < 4; ++r) pc[r] = dacc[r];
                        #pragma unroll
                        for (int uu = 0; uu < 16; ++uu) {
                            float uv = uebt[uu*128 + tloc];
                            #pragma unroll
                            for (int r = 0; r < 4; ++r) {
                                int c = (lq << 2) + r;
                                if (c < 13) pc[r] = fmaf(uv, dwue[uu*13 + c], pc[r]);
                            }
                        }
                        #pragma unroll
                        for (int r = 0; r < 4; ++r) {
                            int c = (lq << 2) + r;
                            if (c < 13) {
                                float v = pc[r] + dense_b[c];
                                if (tglob == 0)    v += left_b[c];
                                if (tglob == NT-1) v += right_b[c];
                                out_pot[(bb*NT + tglob)*13 + c] = v;
                            }
                        }
                    }
                }
                __syncthreads();
            }
            #pragma unroll
            for (int mt = 0; mt < 4; ++mt)
                #pragma unroll
                for (int nt = 0; nt < 2; ++nt) cacc[mt][nt] = (f4v){0.f,0.f,0.f,0.f};
        }
    }
}

// ---------------- viterbi v2: DPP-rotation scan ----------------
__global__ __launch_bounds__(256)
void viterbi_kernel(const float* __restrict__ pot,
                    const float* __restrict__ trans,
                    float* __restrict__ out_dec,
                    float* __restrict__ out_seq,
                    float* __restrict__ out_trans)
{
    __shared__ __align__(16) float s_lds[NT * NC];       // state rows (scan output)
    __shared__ __align__(16) float ptld[16 * PT];        // pot transposed [c][t]
    __shared__ float t_lds[NC * NC];
    __shared__ unsigned char path_lds[16 * 13 * 32];
    __shared__ unsigned char entry_lds[16 * 13];
    __shared__ int chunk_e[16];

    const int b   = blockIdx.x;
    const int tid = threadIdx.x;

    // zero ptld rows 13..15 (read by ring lanes 13..15 -> must not be NaN)
    for (int i = tid; i < 3 * PT; i += 256) ptld[13 * PT + i] = 0.f;
    // stage pot transposed + s row 0 + trans
    for (int i = tid; i < NT * NC; i += 256) {
        int t = i / NC, c = i - t * NC;
        float v = pot[b * NT * NC + i];
        ptld[c * PT + t] = v;
        if (t == 0) s_lds[c] = v;
    }
    for (int i = tid; i < NC * NC; i += 256) t_lds[i] = trans[i];
    __syncthreads();

    // ---- forward scan: lanes 0..15 of wave 0, DPP row_ror:1 ring ----
    if (tid < 16) {
        const int c = tid;
        // runtime rotation-direction detection (wave-uniform)
        int r1 = __builtin_amdgcn_mov_dpp(c, 0x121, 0xF, 0xF, false);
        const bool fwd = (r1 == ((c + 1) & 15));
        float tc[16];
        #pragma unroll
        for (int k = 0; k < 16; ++k) {
            int p = fwd ? ((c + k) & 15) : ((c - k) & 15);
            tc[k] = (c < 13 && p < 13) ? t_lds[p * NC + c] : -1e30f;
        }
        float s = (c < 13) ? s_lds[c] : -1e30f;
        int t = 1;

        auto step = [&](float pv) {
            float acc = s + tc[0];
            float r = s;
            #pragma unroll
            for (int k = 1; k < 16; ++k) {
                r = __int_as_float(__builtin_amdgcn_mov_dpp(
                        __float_as_int(r), 0x121, 0xF, 0xF, false));
                acc = fmaxf(acc, r + tc[k]);
            }
            s = acc + pv;   // max value is order-invariant -> bit-exact vs ref
            if (c < 13) s_lds[t * NC + c] = s;
            ++t;
        };

        const float* prow = &ptld[c * PT];
        float4 pvv = *(const float4*)&prow[4];
        step(prow[1]);
        step(prow[2]);
        step(prow[3]);
        #pragma unroll 1
        for (int t4 = 4; t4 < NT; t4 += 4) {
            float4 cur = pvv;
            if (t4 + 4 < NT) pvv = *(const float4*)&prow[t4 + 4];
            step(cur.x); step(cur.y); step(cur.z); step(cur.w);
        }
    }
    __syncthreads();

    // ---- speculative chunk-parallel backpointer recomputation ----
    if (tid < 16 * 13) {
        const int chunk = tid / 13;
        const int e     = tid - chunk * 13;
        unsigned char* path = &path_lds[(chunk * 13 + e) * 32];
        int cur = e;
        path[31] = (unsigned char)e;
        for (int tl = 31; tl >= 1; --tl) {
            const float* srow = &s_lds[(chunk * 32 + tl - 1) * NC];
            float best = -1e30f; int bi = 0;
            #pragma unroll
            for (int p = 0; p < NC; ++p) {
                float v = srow[p] + t_lds[p * NC + cur];
                if (v > best) { best = v; bi = p; }   // first-max (jnp.argmax)
            }
            cur = bi;
            path[tl - 1] = (unsigned char)cur;
        }
        if (chunk > 0) {
            const float* srow = &s_lds[(chunk * 32 - 1) * NC];
            float best = -1e30f; int bi = 0;
            #pragma unroll
            for (int p = 0; p < NC; ++p) {
                float v = srow[p] + t_lds[p * NC + cur];
                if (v > best) { best = v; bi = p; }
            }
            entry_lds[chunk * 13 + e] = (unsigned char)bi;
        }
    }
    __syncthreads();

    if (tid == 0) {
        float best = -1e30f; int last = 0;
        for (int c = 0; c < NC; ++c) {
            float v = s_lds[(NT - 1) * NC + c];
            if (v > best) { best = v; last = c; }
        }
        chunk_e[15] = last;
        for (int i = 15; i >= 1; --i)
            chunk_e[i - 1] = entry_lds[i * 13 + chunk_e[i]];
    }
    __syncthreads();

    float* dec = out_dec + b * NT;
    for (int t = tid; t < NT; t += 256) {
        int ck = t >> 5;
        dec[t] = (float)path_lds[(ck * 13 + chunk_e[ck]) * 32 + (t & 31)];
    }
    if (tid == 0) out_seq[b] = (float)NT;
    if (b == 0) {
        for (int i = tid; i < NC * NC; i += 256) out_trans[i] = trans[i];
    }
}

extern "C" void kernel_launch(void* const* d_in, const int* in_sizes, int n_in,
                              void* d_out, int out_size, void* d_ws, size_t ws_size,
                              hipStream_t stream) {
    const int*   input_char   = (const int*)d_in[0];
    const int*   input_script = (const int*)d_in[1];
    const float* char_emb     = (const float*)d_in[3];
    const float* uscript_emb  = (const float*)d_in[4];
    const float* dense_w      = (const float*)d_in[5];
    const float* dense_b      = (const float*)d_in[6];
    const float* trans        = (const float*)d_in[7];
    const float* left_b       = (const float*)d_in[8];
    const float* right_b      = (const float*)d_in[9];
    const float* cw1 = (const float*)d_in[10];
    const float* cb1 = (const float*)d_in[11];
    const float* cw2 = (const float*)d_in[12];
    const float* cb2 = (const float*)d_in[13];
    const float* cw3 = (const float*)d_in[14];
    const float* cb3 = (const float*)d_in[15];
    const float* cw4 = (const float*)d_in[16];
    const float* cb4 = (const float*)d_in[17];
    const float* cw5 = (const float*)d_in[18];
    const float* cb5 = (const float*)d_in[19];

    float* out       = (float*)d_out;
    float* out_dec   = out;                       // [B,T] decoded tags (as float)
    float* out_pot   = out + NB * NT;             // [B,T,C]
    float* out_seq   = out_pot + NB * NT * NC;    // [B]
    float* out_trans = out_seq + NB;              // [C,C]

    if (ws_size >= (size_t)WS_NEED) {
        hipLaunchKernelGGL(prep_kernel, dim3(35), dim3(512), 0, stream,
                           cw1, cw2, cw3, cw4, cw5, dense_w, (ush*)d_ws);
        hipLaunchKernelGGL(pot_kernel_ws, dim3(256), dim3(512), 0, stream,
                           input_char, input_script, char_emb, uscript_emb,
                           dense_w, dense_b, left_b, right_b,
                           cb1, cb2, cb3, cb4, cb5,
                           (const ush*)d_ws, out_pot);
    } else {
        hipLaunchKernelGGL(pot_kernel_fb, dim3(256), dim3(512), 0, stream,
                           input_char, input_script, char_emb, uscript_emb,
                           dense_w, dense_b, left_b, right_b,
                           cw1, cb1, cw2, cb2, cw3, cb3, cw4, cb4, cw5, cb5,
                           out_pot);
    }

    hipLaunchKernelGGL(viterbi_kernel, dim3(NB), dim3(256), 0, stream,
                       out_pot, trans, out_dec, out_seq, out_trans);
}

// Round 8
// 155.682 us; speedup vs baseline: 1.4816x; 1.0109x over previous
//
#include <hip/hip_runtime.h>

#define NB 64
#define NT 512
#define NC 13
#define AP 136    // A row stride (ush)
#define WP 72     // W row stride (ush)
#define PT 516    // transposed-pot row stride (floats)
#define USTRIDE 18432            // ush per W unit (hi 9216 + lo 9216) = 36864 B
#define DWT_H   552960           // 30*18432
#define DWT_L   563200           // DWT_H + 5*2048
#define WS_NEED 1146880          // bytes

typedef short s8v __attribute__((ext_vector_type(8)));
typedef float f4v __attribute__((ext_vector_type(4)));
typedef unsigned short ush;
typedef unsigned int u32;

__device__ __forceinline__ ush f2bf(float f){
    union { float f; u32 u; } v; v.f = f;
    u32 r = v.u + 0x7fffu + ((v.u >> 16) & 1u);
    return (ush)(r >> 16);
}
__device__ __forceinline__ float bf2f(ush h){
    union { u32 u; float f; } v; v.u = ((u32)h) << 16; return v.f;
}

// ---- prep: pre-split W (+ dwT) into ws in pot's exact padded LDS layout ----
__global__ __launch_bounds__(512)
void prep_kernel(const float* __restrict__ cw1, const float* __restrict__ cw2,
                 const float* __restrict__ cw3, const float* __restrict__ cw4,
                 const float* __restrict__ cw5, const float* __restrict__ dense_w,
                 ush* __restrict__ ws)
{
    int bx = blockIdx.x, tid = threadIdx.x;
    if (bx < 30) {
        int u = bx, ut = u >> 1, eh = u & 1;
        int fb = ut<1?0: ut<3?1: ut<6?2: ut<10?3:4;
        int jj = ut - fb*(fb+1)/2;
        const float* cw = fb==0?cw1: fb==1?cw2: fb==2?cw3: fb==3?cw4: cw5;
        #pragma unroll
        for (int it = 0; it < 2; ++it) {
            int g = it*512 + tid;            // 0..1023
            int f = g & 127;
            int e8 = (g >> 7) << 3;          // 0..56
            float v[8];
            #pragma unroll
            for (int q = 0; q < 8; ++q)
                v[q] = cw[(jj*128 + eh*64 + e8 + q)*128 + f];
            ush h8[8], l8[8];
            #pragma unroll
            for (int q = 0; q < 8; ++q) {
                h8[q] = f2bf(v[q]);
                l8[q] = f2bf(v[q] - bf2f(h8[q]));
            }
            uint4 hv, lv;
            hv.x = h8[0] | ((u32)h8[1]<<16); hv.y = h8[2] | ((u32)h8[3]<<16);
            hv.z = h8[4] | ((u32)h8[5]<<16); hv.w = h8[6] | ((u32)h8[7]<<16);
            lv.x = l8[0] | ((u32)l8[1]<<16); lv.y = l8[2] | ((u32)l8[3]<<16);
            lv.z = l8[4] | ((u32)l8[5]<<16); lv.w = l8[6] | ((u32)l8[7]<<16);
            *(uint4*)&ws[u*USTRIDE + f*WP + e8]        = hv;
            *(uint4*)&ws[u*USTRIDE + 9216 + f*WP + e8] = lv;
        }
    } else {
        int fb = bx - 30;
        #pragma unroll
        for (int it = 0; it < 4; ++it) {
            int idx = it*512 + tid;          // 0..2047 = c*128+f
            int c = idx >> 7, f = idx & 127;
            float v = (c < 13) ? dense_w[(fb*128 + f)*13 + c] : 0.f;
            ush hi = f2bf(v);
            ws[DWT_H + fb*2048 + idx] = hi;
            ws[DWT_L + fb*2048 + idx] = f2bf(v - bf2f(hi));
        }
    }
}

// ---- pot v6: gll double-buffered W staging (static LDS) — unchanged ----
__global__ __launch_bounds__(512)
void pot_kernel_ws(const int* __restrict__ input_char,
                   const int* __restrict__ input_script,
                   const float* __restrict__ char_emb,
                   const float* __restrict__ uscript_emb,
                   const float* __restrict__ dense_w,
                   const float* __restrict__ dense_b,
                   const float* __restrict__ left_b,
                   const float* __restrict__ right_b,
                   const float* __restrict__ cb1, const float* __restrict__ cb2,
                   const float* __restrict__ cb3, const float* __restrict__ cb4,
                   const float* __restrict__ cb5,
                   const ush* __restrict__ ws,
                   float* __restrict__ out_pot)
{
    __shared__ __align__(16) ush smem[77280];           // 154560 B
    ush* Ah     = smem;                                 // 132 x AP
    ush* Al     = smem + 17952;
    ush* feat_h = smem + 54336;                         // aliases buf1 (fb-end only)
    ush* feat_l = smem + 63040;
    float* uebt = (float*)(smem + 72768);               // 16 x 128 fp32
    float* dwue = (float*)(smem + 76864);               // 16 x 13 fp32

    const int tid  = threadIdx.x;
    const int lane = tid & 63;
    const int wid  = tid >> 6;
    const int tg   = wid >> 2;
    const int fg   = wid & 3;
    const int lr   = lane & 15;
    const int lq   = lane >> 4;
    const int bb   = blockIdx.x >> 2;
    const int t0   = (blockIdx.x & 3) << 7;

    // ---- issue gll for unit 0 into buf0 (overlaps A staging) ----
    {
        const char* g = (const char*)ws;
        char* l = (char*)(smem + 35904);
        #pragma unroll
        for (int i = 0; i < 5; ++i) {
            int idx = wid + (i << 3);
            if (i < 4 || wid < 4)
                __builtin_amdgcn_global_load_lds(
                    (const __attribute__((address_space(1))) void*)(g + idx*1024 + lane*16),
                    (__attribute__((address_space(3))) void*)(l + idx*1024 + lane*16), 16, 0, 0);
        }
    }

    // ---- stage A: emb rows t0-2 .. t0+129, fp32 -> bf16 hi/lo ----
    for (int i = tid; i < 132*16; i += 512) {
        int row = i >> 4, s = (i & 15) << 3;
        int t = t0 + row - 2;
        uint4 hv = {0,0,0,0}, lv = {0,0,0,0};
        if (t >= 0 && t < NT) {
            int ch = input_char[bb*NT + t];
            const float* src = char_emb + ch*128 + s;
            float4 x0 = *(const float4*)src;
            float4 x1 = *(const float4*)(src + 4);
            float fs[8] = {x0.x,x0.y,x0.z,x0.w,x1.x,x1.y,x1.z,x1.w};
            ush h[8], l[8];
            #pragma unroll
            for (int q = 0; q < 8; ++q) {
                h[q] = f2bf(fs[q]);
                l[q] = f2bf(fs[q] - bf2f(h[q]));
            }
            hv.x = h[0] | ((u32)h[1]<<16); hv.y = h[2] | ((u32)h[3]<<16);
            hv.z = h[4] | ((u32)h[5]<<16); hv.w = h[6] | ((u32)h[7]<<16);
            lv.x = l[0] | ((u32)l[1]<<16); lv.y = l[2] | ((u32)l[3]<<16);
            lv.z = l[4] | ((u32)l[5]<<16); lv.w = l[6] | ((u32)l[7]<<16);
        }
        *(uint4*)&Ah[row*AP + s] = hv;
        *(uint4*)&Al[row*AP + s] = lv;
    }
    // ---- stage uebt / dwue (fp32, exact) ----
    for (int i = tid; i < 2048; i += 512) {
        int uu = i >> 7, tl = i & 127;
        uebt[uu*128 + tl] = uscript_emb[input_script[bb*NT + t0 + tl]*16 + uu];
    }
    if (tid < 208) dwue[tid] = dense_w[640*13 + tid];
    __syncthreads();

    const float* cbs[5] = {cb1, cb2, cb3, cb4, cb5};

    f4v cacc[4][2];
    #pragma unroll
    for (int mt = 0; mt < 4; ++mt)
        #pragma unroll
        for (int nt = 0; nt < 2; ++nt) cacc[mt][nt] = (f4v){0.f,0.f,0.f,0.f};
    f4v dacc = (f4v){0.f,0.f,0.f,0.f};

    #pragma unroll 1
    for (int u = 0; u < 30; ++u) {
        int ut  = u >> 1, eh = u & 1;
        int fb  = ut<1?0: ut<3?1: ut<6?2: ut<10?3:4;
        int jj  = ut - fb*(fb+1)/2;
        int jsh = (2 - (fb >> 1)) + jj;

        // ---- issue gll for next unit into the other buffer ----
        if (u < 29) {
            const char* g = (const char*)ws + (u + 1)*36864;
            char* l = (char*)(smem + (((u + 1) & 1) ? 54336 : 35904));
            #pragma unroll
            for (int i = 0; i < 5; ++i) {
                int idx = wid + (i << 3);
                if (i < 4 || wid < 4)
                    __builtin_amdgcn_global_load_lds(
                        (const __attribute__((address_space(1))) void*)(g + idx*1024 + lane*16),
                        (__attribute__((address_space(3))) void*)(l + idx*1024 + lane*16), 16, 0, 0);
            }
        }

        // ---- conv MFMA: 48 per wave, from buf[u&1] ----
        const ush* Wh = smem + ((u & 1) ? 54336 : 35904);
        const ush* Wl = Wh + 9216;
        #pragma unroll
        for (int kk = 0; kk < 2; ++kk) {
            int ko = kk*32 + (lq << 3);
            s8v bh[2], bl[2];
            #pragma unroll
            for (int nt = 0; nt < 2; ++nt) {
                int frow = fg*32 + nt*16 + lr;
                bh[nt] = *(const s8v*)&Wh[frow*WP + ko];
                bl[nt] = *(const s8v*)&Wl[frow*WP + ko];
            }
            #pragma unroll
            for (int mt = 0; mt < 4; ++mt) {
                int row = tg*64 + mt*16 + lr + jsh;
                int ai  = row*AP + eh*64 + ko;
                s8v ah = *(const s8v*)&Ah[ai];
                s8v al = *(const s8v*)&Al[ai];
                #pragma unroll
                for (int nt = 0; nt < 2; ++nt) {
                    cacc[mt][nt] = __builtin_amdgcn_mfma_f32_16x16x32_bf16(ah, bh[nt], cacc[mt][nt], 0,0,0);
                    cacc[mt][nt] = __builtin_amdgcn_mfma_f32_16x16x32_bf16(ah, bl[nt], cacc[mt][nt], 0,0,0);
                    cacc[mt][nt] = __builtin_amdgcn_mfma_f32_16x16x32_bf16(al, bh[nt], cacc[mt][nt], 0,0,0);
                }
            }
        }

        // ---- end of an f-block (u odd): ReLU -> feat (aliases buf1) -> dense ----
        if (u == 1 || u == 5 || u == 11 || u == 19 || u == 29) {
            __syncthreads();   // all conv reads of buf1 done; safe to write feat
            float cbv0 = cbs[fb][fg*32 + lr];
            float cbv1 = cbs[fb][fg*32 + 16 + lr];

            #pragma unroll 1
            for (int h = 0; h < 2; ++h) {
                if (tg == h) {
                    #pragma unroll
                    for (int mt = 0; mt < 4; ++mt)
                        #pragma unroll
                        for (int nt = 0; nt < 2; ++nt)
                            #pragma unroll
                            for (int r = 0; r < 4; ++r) {
                                float v = fmaxf(cacc[mt][nt][r] + (nt ? cbv1 : cbv0), 0.f);
                                int rw = mt*16 + (lq << 2) + r;       // local t in half
                                int f  = fg*32 + nt*16 + lr;
                                ush hh = f2bf(v);
                                feat_h[rw*AP + f] = hh;
                                feat_l[rw*AP + f] = f2bf(v - bf2f(hh));
                            }
                }
                __syncthreads();
                if (tg == h) {
                    int trow = fg*16 + lr;                            // local t in half
                    #pragma unroll
                    for (int kf = 0; kf < 4; ++kf) {
                        int f0 = kf*32 + (lq << 3);
                        s8v a2h = *(const s8v*)&ws[DWT_H + fb*2048 + lr*128 + f0];
                        s8v a2l = *(const s8v*)&ws[DWT_L + fb*2048 + lr*128 + f0];
                        s8v b2h = *(const s8v*)&feat_h[trow*AP + f0];
                        s8v b2l = *(const s8v*)&feat_l[trow*AP + f0];
                        dacc = __builtin_amdgcn_mfma_f32_16x16x32_bf16(a2h, b2h, dacc, 0,0,0);
                        dacc = __builtin_amdgcn_mfma_f32_16x16x32_bf16(a2h, b2l, dacc, 0,0,0);
                        dacc = __builtin_amdgcn_mfma_f32_16x16x32_bf16(a2l, b2h, dacc, 0,0,0);
                    }
                    if (fb == 4) {
                        int tloc  = tg*64 + fg*16 + lr;
                        int tglob = t0 + tloc;
                        float pc[4];
                        #pragma unroll
                        for (int r = 0; r < 4; ++r) pc[r] = dacc[r];
                        #pragma unroll
                        for (int uu = 0; uu < 16; ++uu) {
                            float uv = uebt[uu*128 + tloc];
                            #pragma unroll
                            for (int r = 0; r < 4; ++r) {
                                int c = (lq << 2) + r;
                                if (c < 13) pc[r] = fmaf(uv, dwue[uu*13 + c], pc[r]);
                            }
                        }
                        #pragma unroll
                        for (int r = 0; r < 4; ++r) {
                            int c = (lq << 2) + r;
                            if (c < 13) {
                                float v = pc[r] + dense_b[c];
                                if (tglob == 0)    v += left_b[c];
                                if (tglob == NT-1) v += right_b[c];
                                out_pot[(bb*NT + tglob)*13 + c] = v;
                            }
                        }
                    }
                }
                __syncthreads();
            }
            #pragma unroll
            for (int mt = 0; mt < 4; ++mt)
                #pragma unroll
                for (int nt = 0; nt < 2; ++nt) cacc[mt][nt] = (f4v){0.f,0.f,0.f,0.f};
        } else {
            __syncthreads();   // drains this wave's gll (vmcnt) + publishes buffers
        }
    }
}

// ---- fallback pot (round-4 verbatim, used if ws_size too small) ----
__global__ __launch_bounds__(512)
void pot_kernel_fb(const int* __restrict__ input_char,
                   const int* __restrict__ input_script,
                   const float* __restrict__ char_emb,
                   const float* __restrict__ uscript_emb,
                   const float* __restrict__ dense_w,
                   const float* __restrict__ dense_b,
                   const float* __restrict__ left_b,
                   const float* __restrict__ right_b,
                   const float* __restrict__ cw1, const float* __restrict__ cb1,
                   const float* __restrict__ cw2, const float* __restrict__ cb2,
                   const float* __restrict__ cw3, const float* __restrict__ cb3,
                   const float* __restrict__ cw4, const float* __restrict__ cb4,
                   const float* __restrict__ cw5, const float* __restrict__ cb5,
                   float* __restrict__ out_pot)
{
    __shared__ __align__(16) ush smem[71744];
    ush* Ah     = smem;
    ush* Al     = smem + 17952;
    ush* Wh     = smem + 35904;
    ush* Wl     = smem + 45120;
    ush* feat_h = smem + 54336;
    ush* feat_l = smem + 63040;
    float* dwlds = (float*)(smem + 35904);
    float* dwue  = (float*)(smem + 39232);
    float* uebt  = (float*)(smem + 39648);

    const int tid  = threadIdx.x;
    const int lane = tid & 63;
    const int wid  = tid >> 6;
    const int tg   = wid >> 2;
    const int fg   = wid & 3;
    const int lr   = lane & 15;
    const int lq   = lane >> 4;
    const int bb   = blockIdx.x >> 2;
    const int t0   = (blockIdx.x & 3) << 7;

    for (int i = tid; i < 132*16; i += 512) {
        int row = i >> 4, s = (i & 15) << 3;
        int t = t0 + row - 2;
        uint4 hv = {0,0,0,0}, lv = {0,0,0,0};
        if (t >= 0 && t < NT) {
            int ch = input_char[bb*NT + t];
            const float* src = char_emb + ch*128 + s;
            float4 x0 = *(const float4*)src;
            float4 x1 = *(const float4*)(src + 4);
            float fs[8] = {x0.x,x0.y,x0.z,x0.w,x1.x,x1.y,x1.z,x1.w};
            ush h[8], l[8];
            #pragma unroll
            for (int q = 0; q < 8; ++q) {
                h[q] = f2bf(fs[q]);
                l[q] = f2bf(fs[q] - bf2f(h[q]));
            }
            hv.x = h[0] | ((u32)h[1]<<16); hv.y = h[2] | ((u32)h[3]<<16);
            hv.z = h[4] | ((u32)h[5]<<16); hv.w = h[6] | ((u32)h[7]<<16);
            lv.x = l[0] | ((u32)l[1]<<16); lv.y = l[2] | ((u32)l[3]<<16);
            lv.z = l[4] | ((u32)l[5]<<16); lv.w = l[6] | ((u32)l[7]<<16);
        }
        *(uint4*)&Ah[row*AP + s] = hv;
        *(uint4*)&Al[row*AP + s] = lv;
    }

    const float* cws[5] = {cw1, cw2, cw3, cw4, cw5};
    const float* cbs[5] = {cb1, cb2, cb3, cb4, cb5};

    f4v cacc[4][2];
    #pragma unroll
    for (int mt = 0; mt < 4; ++mt)
        #pragma unroll
        for (int nt = 0; nt < 2; ++nt) cacc[mt][nt] = (f4v){0.f,0.f,0.f,0.f};
    f4v dacc = (f4v){0.f,0.f,0.f,0.f};

    #pragma unroll 1
    for (int u = 0; u < 30; ++u) {
        int ut  = u >> 1, eh = u & 1;
        int fb  = ut<1?0: ut<3?1: ut<6?2: ut<10?3:4;
        int jj  = ut - fb*(fb+1)/2;
        int jsh = (2 - (fb >> 1)) + jj;
        const float* cw = cws[fb] + (jj*128 + eh*64)*128;

        __syncthreads();
        for (int g = tid; g < 1024; g += 512) {
            int f = g & 127, e8 = (g >> 7) << 3;
            float v[8];
            #pragma unroll
            for (int q = 0; q < 8; ++q) v[q] = cw[(e8 + q)*128 + f];
            ush h8[8], l8[8];
            #pragma unroll
            for (int q = 0; q < 8; ++q) {
                h8[q] = f2bf(v[q]);
                l8[q] = f2bf(v[q] - bf2f(h8[q]));
            }
            uint4 hv, lv;
            hv.x = h8[0] | ((u32)h8[1]<<16); hv.y = h8[2] | ((u32)h8[3]<<16);
            hv.z = h8[4] | ((u32)h8[5]<<16); hv.w = h8[6] | ((u32)h8[7]<<16);
            lv.x = l8[0] | ((u32)l8[1]<<16); lv.y = l8[2] | ((u32)l8[3]<<16);
            lv.z = l8[4] | ((u32)l8[5]<<16); lv.w = l8[6] | ((u32)l8[7]<<16);
            *(uint4*)&Wh[f*WP + e8] = hv;
            *(uint4*)&Wl[f*WP + e8] = lv;
        }
        __syncthreads();

        #pragma unroll
        for (int kk = 0; kk < 2; ++kk) {
            int ko = kk*32 + (lq << 3);
            s8v bh[2], bl[2];
            #pragma unroll
            for (int nt = 0; nt < 2; ++nt) {
                int frow = fg*32 + nt*16 + lr;
                bh[nt] = *(const s8v*)&Wh[frow*WP + ko];
                bl[nt] = *(const s8v*)&Wl[frow*WP + ko];
            }
            #pragma unroll
            for (int mt = 0; mt < 4; ++mt) {
                int row = tg*64 + mt*16 + lr + jsh;
                int ai  = row*AP + eh*64 + ko;
                s8v ah = *(const s8v*)&Ah[ai];
                s8v al = *(const s8v*)&Al[ai];
                #pragma unroll
                for (int nt = 0; nt < 2; ++nt) {
                    cacc[mt][nt] = __builtin_amdgcn_mfma_f32_16x16x32_bf16(ah, bh[nt], cacc[mt][nt], 0,0,0);
                    cacc[mt][nt] = __builtin_amdgcn_mfma_f32_16x16x32_bf16(ah, bl[nt], cacc[mt][nt], 0,0,0);
                    cacc[mt][nt] = __builtin_amdgcn_mfma_f32_16x16x32_bf16(al, bh[nt], cacc[mt][nt], 0,0,0);
                }
            }
        }

        if (u == 1 || u == 5 || u == 11 || u == 19 || u == 29) {
            __syncthreads();
            for (int i = tid; i < 128*13; i += 512)
                dwlds[i] = dense_w[fb*128*13 + i];
            if (fb == 4) {
                for (int i = tid; i < 16*13; i += 512)
                    dwue[i] = dense_w[640*13 + i];
                for (int i = tid; i < 2048; i += 512) {
                    int uu = i >> 7, tl = i & 127;
                    uebt[uu*128 + tl] = uscript_emb[input_script[bb*NT + t0 + tl]*16 + uu];
                }
            }
            __syncthreads();

            float cbv0 = cbs[fb][fg*32 + lr];
            float cbv1 = cbs[fb][fg*32 + 16 + lr];

            #pragma unroll 1
            for (int h = 0; h < 2; ++h) {
                if (tg == h) {
                    #pragma unroll
                    for (int mt = 0; mt < 4; ++mt)
                        #pragma unroll
                        for (int nt = 0; nt < 2; ++nt)
                            #pragma unroll
                            for (int r = 0; r < 4; ++r) {
                                float v = fmaxf(cacc[mt][nt][r] + (nt ? cbv1 : cbv0), 0.f);
                                int rw = mt*16 + (lq << 2) + r;
                                int f  = fg*32 + nt*16 + lr;
                                ush hh = f2bf(v);
                                feat_h[rw*AP + f] = hh;
                                feat_l[rw*AP + f] = f2bf(v - bf2f(hh));
                            }
                }
                __syncthreads();
                if (tg == h) {
                    int trow = fg*16 + lr;
                    #pragma unroll
                    for (int kf = 0; kf < 4; ++kf) {
                        int f0 = kf*32 + (lq << 3);
                        float dv[8];
                        #pragma unroll
                        for (int q = 0; q < 8; ++q) dv[q] = dwlds[(f0 + q)*13 + lr];
                        s8v a2h, a2l;
                        #pragma unroll
                        for (int q = 0; q < 8; ++q) {
                            ush hh = f2bf(dv[q]);
                            a2h[q] = (short)hh;
                            a2l[q] = (short)f2bf(dv[q] - bf2f(hh));
                        }
                        s8v b2h = *(const s8v*)&feat_h[trow*AP + f0];
                        s8v b2l = *(const s8v*)&feat_l[trow*AP + f0];
                        dacc = __builtin_amdgcn_mfma_f32_16x16x32_bf16(a2h, b2h, dacc, 0,0,0);
                        dacc = __builtin_amdgcn_mfma_f32_16x16x32_bf16(a2h, b2l, dacc, 0,0,0);
                        dacc = __builtin_amdgcn_mfma_f32_16x16x32_bf16(a2l, b2h, dacc, 0,0,0);
                    }
                    if (fb == 4) {
                        int tloc  = tg*64 + fg*16 + lr;
                        int tglob = t0 + tloc;
                        float pc[4];
                        #pragma unroll
                        for (int r = 0; r < 4; ++r) pc[r] = dacc[r];
                        #pragma unroll
                        for (int uu = 0; uu < 16; ++uu) {
                            float uv = uebt[uu*128 + tloc];
                            #pragma unroll
                            for (int r = 0; r < 4; ++r) {
                                int c = (lq << 2) + r;
                                if (c < 13) pc[r] = fmaf(uv, dwue[uu*13 + c], pc[r]);
                            }
                        }
                        #pragma unroll
                        for (int r = 0; r < 4; ++r) {
                            int c = (lq << 2) + r;
                            if (c < 13) {
                                float v = pc[r] + dense_b[c];
                                if (tglob == 0)    v += left_b[c];
                                if (tglob == NT-1) v += right_b[c];
                                out_pot[(bb*NT + tglob)*13 + c] = v;
                            }
                        }
                    }
                }
                __syncthreads();
            }
            #pragma unroll
            for (int mt = 0; mt < 4; ++mt)
                #pragma unroll
                for (int nt = 0; nt < 2; ++nt) cacc[mt][nt] = (f4v){0.f,0.f,0.f,0.f};
        }
    }
}

// ---------------- viterbi v3: log-depth DPP all-gather scan ----------------
#define DPPF(dst, src, ctrl) \
    dst = __int_as_float(__builtin_amdgcn_mov_dpp(__float_as_int(src), ctrl, 0xF, 0xF, false))

__global__ __launch_bounds__(256)
void viterbi_kernel(const float* __restrict__ pot,
                    const float* __restrict__ trans,
                    float* __restrict__ out_dec,
                    float* __restrict__ out_seq,
                    float* __restrict__ out_trans)
{
    __shared__ __align__(16) float s_lds[NT * NC];       // state rows (scan output)
    __shared__ __align__(16) float ptld[16 * PT];        // pot transposed [c][t]
    __shared__ float t_lds[NC * NC];
    __shared__ unsigned char path_lds[16 * 13 * 32];
    __shared__ unsigned char entry_lds[16 * 13];
    __shared__ int chunk_e[16];

    const int b   = blockIdx.x;
    const int tid = threadIdx.x;

    // zero ptld rows 13..15 (read by gather lanes 13..15 -> must not be NaN)
    for (int i = tid; i < 3 * PT; i += 256) ptld[13 * PT + i] = 0.f;
    // stage pot transposed + s row 0 + trans
    for (int i = tid; i < NT * NC; i += 256) {
        int t = i / NC, c = i - t * NC;
        float v = pot[b * NT * NC + i];
        ptld[c * PT + t] = v;
        if (t == 0) s_lds[c] = v;
    }
    for (int i = tid; i < NC * NC; i += 256) t_lds[i] = trans[i];
    __syncthreads();

    // ---- forward scan: lanes 0..15 of wave 0, log-depth rotation all-gather ----
    if (tid < 16) {
        const int c = tid;
        // runtime rotation-direction detection (wave-uniform)
        int r1 = __builtin_amdgcn_mov_dpp(c, 0x121, 0xF, 0xF, false);
        const bool fwd = (r1 == ((c + 1) & 15));
        float tc[16];
        #pragma unroll
        for (int k = 0; k < 16; ++k) {
            int p = fwd ? ((c + k) & 15) : ((c - k) & 15);
            tc[k] = (c < 13 && p < 13) ? t_lds[p * NC + c] : -1e30f;
        }
        float s = (c < 13) ? s_lds[c] : -1e30f;
        int t = 1;

        // v[k] = s[(c +/- k)&15], built with dependency depth 4 (1,2,4,8)
        auto step = [&](float pv) {
            float v0 = s, v1, v2, v3, v4, v5, v6, v7;
            float v8, v9, v10, v11, v12, v13, v14, v15;
            DPPF(v1, v0, 0x121);                     // ror 1
            DPPF(v2, v0, 0x122); DPPF(v3, v1, 0x122);// ror 2
            DPPF(v4, v0, 0x124); DPPF(v5, v1, 0x124);
            DPPF(v6, v2, 0x124); DPPF(v7, v3, 0x124);// ror 4
            DPPF(v8,  v0, 0x128); DPPF(v9,  v1, 0x128);
            DPPF(v10, v2, 0x128); DPPF(v11, v3, 0x128);
            DPPF(v12, v4, 0x128); DPPF(v13, v5, 0x128);
            DPPF(v14, v6, 0x128); DPPF(v15, v7, 0x128); // ror 8
            float m0 = fmaxf(v0  + tc[0],  v1  + tc[1]);
            float m1 = fmaxf(v2  + tc[2],  v3  + tc[3]);
            float m2 = fmaxf(v4  + tc[4],  v5  + tc[5]);
            float m3 = fmaxf(v6  + tc[6],  v7  + tc[7]);
            float m4 = fmaxf(v8  + tc[8],  v9  + tc[9]);
            float m5 = fmaxf(v10 + tc[10], v11 + tc[11]);
            float m6 = fmaxf(v12 + tc[12], v13 + tc[13]);
            float m7 = fmaxf(v14 + tc[14], v15 + tc[15]);
            float n0 = fmaxf(m0, m1), n1 = fmaxf(m2, m3);
            float n2 = fmaxf(m4, m5), n3 = fmaxf(m6, m7);
            s = fmaxf(fmaxf(n0, n1), fmaxf(n2, n3)) + pv;
            if (c < 13) s_lds[t * NC + c] = s;
            ++t;
        };

        const float* prow = &ptld[c * PT];
        float4 pvv = *(const float4*)&prow[4];
        step(prow[1]);
        step(prow[2]);
        step(prow[3]);
        #pragma unroll 1
        for (int t4 = 4; t4 < NT; t4 += 4) {
            float4 cur = pvv;
            if (t4 + 4 < NT) pvv = *(const float4*)&prow[t4 + 4];
            step(cur.x); step(cur.y); step(cur.z); step(cur.w);
        }
    }
    __syncthreads();

    // ---- speculative chunk-parallel backpointer recomputation ----
    if (tid < 16 * 13) {
        const int chunk = tid / 13;
        const int e     = tid - chunk * 13;
        unsigned char* path = &path_lds[(chunk * 13 + e) * 32];
        int cur = e;
        path[31] = (unsigned char)e;
        for (int tl = 31; tl >= 1; --tl) {
            const float* srow = &s_lds[(chunk * 32 + tl - 1) * NC];
            float best = -1e30f; int bi = 0;
            #pragma unroll
            for (int p = 0; p < NC; ++p) {
                float v = srow[p] + t_lds[p * NC + cur];
                if (v > best) { best = v; bi = p; }   // first-max (jnp.argmax)
            }
            cur = bi;
            path[tl - 1] = (unsigned char)cur;
        }
        if (chunk > 0) {
            const float* srow = &s_lds[(chunk * 32 - 1) * NC];
            float best = -1e30f; int bi = 0;
            #pragma unroll
            for (int p = 0; p < NC; ++p) {
                float v = srow[p] + t_lds[p * NC + cur];
                if (v > best) { best = v; bi = p; }
            }
            entry_lds[chunk * 13 + e] = (unsigned char)bi;
        }
    }
    __syncthreads();

    if (tid == 0) {
        float best = -1e30f; int last = 0;
        for (int c = 0; c < NC; ++c) {
            float v = s_lds[(NT - 1) * NC + c];
            if (v > best) { best = v; last = c; }
        }
        chunk_e[15] = last;
        for (int i = 15; i >= 1; --i)
            chunk_e[i - 1] = entry_lds[i * 13 + chunk_e[i]];
    }
    __syncthreads();

    float* dec = out_dec + b * NT;
    for (int t = tid; t < NT; t += 256) {
        int ck = t >> 5;
        dec[t] = (float)path_lds[(ck * 13 + chunk_e[ck]) * 32 + (t & 31)];
    }
    if (tid == 0) out_seq[b] = (float)NT;
    if (b == 0) {
        for (int i = tid; i < NC * NC; i += 256) out_trans[i] = trans[i];
    }
}

extern "C" void kernel_launch(void* const* d_in, const int* in_sizes, int n_in,
                              void* d_out, int out_size, void* d_ws, size_t ws_size,
                              hipStream_t stream) {
    const int*   input_char   = (const int*)d_in[0];
    const int*   input_script = (const int*)d_in[1];
    const float* char_emb     = (const float*)d_in[3];
    const float* uscript_emb  = (const float*)d_in[4];
    const float* dense_w      = (const float*)d_in[5];
    const float* dense_b      = (const float*)d_in[6];
    const float* trans        = (const float*)d_in[7];
    const float* left_b       = (const float*)d_in[8];
    const float* right_b      = (const float*)d_in[9];
    const float* cw1 = (const float*)d_in[10];
    const float* cb1 = (const float*)d_in[11];
    const float* cw2 = (const float*)d_in[12];
    const float* cb2 = (const float*)d_in[13];
    const float* cw3 = (const float*)d_in[14];
    const float* cb3 = (const float*)d_in[15];
    const float* cw4 = (const float*)d_in[16];
    const float* cb4 = (const float*)d_in[17];
    const float* cw5 = (const float*)d_in[18];
    const float* cb5 = (const float*)d_in[19];

    float* out       = (float*)d_out;
    float* out_dec   = out;                       // [B,T] decoded tags (as float)
    float* out_pot   = out + NB * NT;             // [B,T,C]
    float* out_seq   = out_pot + NB * NT * NC;    // [B]
    float* out_trans = out_seq + NB;              // [C,C]

    if (ws_size >= (size_t)WS_NEED) {
        hipLaunchKernelGGL(prep_kernel, dim3(35), dim3(512), 0, stream,
                           cw1, cw2, cw3, cw4, cw5, dense_w, (ush*)d_ws);
        hipLaunchKernelGGL(pot_kernel_ws, dim3(256), dim3(512), 0, stream,
                           input_char, input_script, char_emb, uscript_emb,
                           dense_w, dense_b, left_b, right_b,
                           cb1, cb2, cb3, cb4, cb5,
                           (const ush*)d_ws, out_pot);
    } else {
        hipLaunchKernelGGL(pot_kernel_fb, dim3(256), dim3(512), 0, stream,
                           input_char, input_script, char_emb, uscript_emb,
                           dense_w, dense_b, left_b, right_b,
                           cw1, cb1, cw2, cb2, cw3, cb3, cw4, cb4, cw5, cb5,
                           out_pot);
    }

    hipLaunchKernelGGL(viterbi_kernel, dim3(NB), dim3(256), 0, stream,
                       out_pot, trans, out_dec, out_seq, out_trans);
}